// Round 15
// baseline (569.721 us; speedup 1.0000x reference)
//
#include <hip/hip_runtime.h>
#include <hip/hip_bf16.h>
#include <math.h>

#define DIMC 256
#define INNERC 128
#define HEADSC 4
#define DHC 32
#define QKVC 384

typedef __attribute__((ext_vector_type(8))) short bf16frag;   // 8 bf16 = 4 VGPRs
typedef __attribute__((ext_vector_type(4))) float f32x4;

__device__ __forceinline__ float gelu_exact(float x) {
    return 0.5f * x * (1.0f + erff(x * 0.70710678118654752f));
}

__device__ __forceinline__ float b2f(short s) {
    return __uint_as_float(((unsigned)(unsigned short)s) << 16);
}

__device__ __forceinline__ void gload_lds16(const void* g, void* l) {
    __builtin_amdgcn_global_load_lds(
        (const __attribute__((address_space(1))) void*)g,
        (__attribute__((address_space(3))) void*)l, 16, 0, 0);
}

// ---------------- LayerNorm: one WAVE per row (used once, layer-0 LN1) -----
__global__ __launch_bounds__(256)
void ln_kernel(const float* __restrict__ x, const float* __restrict__ g,
               const float* __restrict__ b, __hip_bfloat16* __restrict__ out,
               int N)
{
    int row = blockIdx.x * 4 + (threadIdx.x >> 6);
    if (row >= N) return;
    int lane = threadIdx.x & 63;
    float4 v = *(const float4*)(x + (size_t)row * DIMC + lane * 4);
    float s = v.x + v.y + v.z + v.w;
    float s2 = v.x * v.x + v.y * v.y + v.z * v.z + v.w * v.w;
#pragma unroll
    for (int off = 32; off; off >>= 1) {
        s += __shfl_xor(s, off);
        s2 += __shfl_xor(s2, off);
    }
    float mean = s * (1.f / DIMC);
    float var = s2 * (1.f / DIMC) - mean * mean;
    float rs = rsqrtf(var + 1e-5f);
    float4 gv = *(const float4*)(g + lane * 4);
    float4 bv = *(const float4*)(b + lane * 4);
    __hip_bfloat16 o[4];
    o[0] = __float2bfloat16((v.x - mean) * rs * gv.x + bv.x);
    o[1] = __float2bfloat16((v.y - mean) * rs * gv.y + bv.y);
    o[2] = __float2bfloat16((v.z - mean) * rs * gv.z + bv.z);
    o[3] = __float2bfloat16((v.w - mean) * rs * gv.w + bv.w);
    *(short4*)(out + (size_t)row * DIMC + lane * 4) = *(short4*)o;
}

// ---------------- fp32 -> bf16 convert (n % 4 == 0) ----------------
__global__ void f2b_kernel(const float* __restrict__ src,
                           __hip_bfloat16* __restrict__ dst, int n)
{
    int i = (blockIdx.x * blockDim.x + threadIdx.x) * 4;
    if (i < n) {
        float4 v = *(const float4*)(src + i);
        dst[i + 0] = __float2bfloat16(v.x);
        dst[i + 1] = __float2bfloat16(v.y);
        dst[i + 2] = __float2bfloat16(v.z);
        dst[i + 3] = __float2bfloat16(v.w);
    }
}

// ---------------- pack wq/wk/wv -> wqkv bf16 [4][384][256], biases [4][384] ----
__global__ __launch_bounds__(256)
void packqkv_kernel(const float* __restrict__ wq, const float* __restrict__ wk,
                    const float* __restrict__ wv, const float* __restrict__ bq,
                    const float* __restrict__ bk, const float* __restrict__ bv,
                    __hip_bfloat16* __restrict__ wqkv, float* __restrict__ bqkv)
{
    int row = blockIdx.x;                 // 0 .. 4*384-1
    int l = row / QKVC, c = row % QKVC;
    int which = c >> 7, cc = c & 127;
    const float* srcw = which == 0 ? wq : which == 1 ? wk : wv;
    const float* srcb = which == 0 ? bq : which == 1 ? bk : bv;
    srcw += ((size_t)l * INNERC + cc) * DIMC;
    wqkv[(size_t)row * DIMC + threadIdx.x] = __float2bfloat16(srcw[threadIdx.x]);
    if (threadIdx.x == 0) bqkv[row] = srcb[l * INNERC + cc];
}

// ---------------- MFMA GEMM v5: 512 thr, 128x128, dbuf + counted vmcnt ------
// (QKV / FF1 — unchanged, proven)
template<int EPI>
__global__ __launch_bounds__(512)
void mfma_gemm(const __hip_bfloat16* __restrict__ A,
               const __hip_bfloat16* __restrict__ W,
               const float* __restrict__ bias, const float* __restrict__ res,
               void* __restrict__ Cout, int M, int K, int OUT,
               int mtiles, int ntiles)
{
    constexpr int ASZ = 128 * 128;          // one A buf (16KB)
    constexpr int WSZ = 128 * 128;          // one W buf (16KB)
    __shared__ char lds[2 * ASZ + 2 * WSZ];

    int nwg = mtiles * ntiles;
    int orig = blockIdx.x;
    int q = nwg >> 3, r = nwg & 7;
    int xcd = orig & 7, loc = orig >> 3;
    int wgid = (xcd < r ? xcd * (q + 1) : r * (q + 1) + (xcd - r) * q) + loc;
    int bm = (wgid / ntiles) * 128;
    int bn = (wgid % ntiles) * 128;

    int tid = threadIdx.x;
    int lane = tid & 63;
    int w = tid >> 6;                        // 0..7
    int wr = w >> 2, wc = w & 3;             // 2 x 4 wave grid
    int l15 = lane & 15, l4 = lane >> 4;

    f32x4 acc[4][2] = {};

    auto stage = [&](int t, int b) {
        int k0 = t * 64;
        char* Asb = lds + b * ASZ;
        char* Wsb = lds + 2 * ASZ + b * WSZ;
#pragma unroll
        for (int it = 0; it < 2; ++it) {             // A: 2 loads/thread
            int chunk = it * 512 + tid;
            int rr = chunk >> 3;
            int sc = (chunk & 7) ^ (rr & 7);
            int grow = min(bm + rr, M - 1);          // clamp: ALWAYS issue
            gload_lds16((const char*)A + ((size_t)grow * K + k0) * 2 + sc * 16,
                        Asb + chunk * 16);
        }
#pragma unroll
        for (int it = 0; it < 2; ++it) {             // W: 2 loads/thread
            int chunk = it * 512 + tid;
            int rr = chunk >> 3;
            int sc = (chunk & 7) ^ (rr & 7);
            gload_lds16((const char*)W + ((size_t)(bn + rr) * K + k0) * 2 + sc * 16,
                        Wsb + chunk * 16);
        }
    };

    int nk = K >> 6;
    stage(0, 0);
    for (int t = 0; t < nk; ++t) {
        int cur = t & 1;
        if (t + 1 < nk) {
            stage(t + 1, cur ^ 1);                   // prefetch into other buf
            asm volatile("s_waitcnt vmcnt(4)" ::: "memory");   // tile t only
        } else {
            asm volatile("s_waitcnt vmcnt(0)" ::: "memory");
        }
        __builtin_amdgcn_s_barrier();                // tile t visible, no drain
        char* As = lds + cur * ASZ;
        char* Ws = lds + 2 * ASZ + cur * WSZ;
#pragma unroll
        for (int s = 0; s < 2; ++s) {
            bf16frag af[4], bfr[2];
            int kb = s * 64 + (l4 << 4);
#pragma unroll
            for (int m = 0; m < 4; ++m) {
                int ar = wr * 64 + m * 16 + l15;
                af[m] = *(const bf16frag*)(As + ar * 128 + (kb ^ ((ar & 7) << 4)));
            }
#pragma unroll
            for (int n = 0; n < 2; ++n) {
                int br = wc * 32 + n * 16 + l15;
                bfr[n] = *(const bf16frag*)(Ws + br * 128 + (kb ^ ((br & 7) << 4)));
            }
#pragma unroll
            for (int m = 0; m < 4; ++m)
#pragma unroll
                for (int n = 0; n < 2; ++n)
                    acc[m][n] = __builtin_amdgcn_mfma_f32_16x16x32_bf16(
                        af[m], bfr[n], acc[m][n], 0, 0, 0);
        }
        __builtin_amdgcn_s_barrier();                // all reads of buf done (WAR)
    }

#pragma unroll
    for (int m = 0; m < 4; ++m)
#pragma unroll
        for (int rr = 0; rr < 4; ++rr) {
            int grow = bm + wr * 64 + m * 16 + (l4 << 2) + rr;
            if (grow < M) {
#pragma unroll
                for (int n = 0; n < 2; ++n) {
                    int gcol = bn + wc * 32 + n * 16 + l15;
                    float val = acc[m][n][rr] + bias[gcol];
                    if (EPI == 1) val = gelu_exact(val);
                    if (EPI == 2) {
                        val += res[(size_t)grow * OUT + gcol];
                        ((float*)Cout)[(size_t)grow * OUT + gcol] = val;
                    } else {
                        ((__hip_bfloat16*)Cout)[(size_t)grow * OUT + gcol] =
                            __float2bfloat16(val);
                    }
                }
            }
        }
}

// ---------------- GEMM+residual+LayerNorm fused (OUT=256, BM=64, BN=256) ----
// outF[M][256] = A @ W^T + bias + res (fp32); if doLN:
// h[M][256] = LN(row) * g + b (bf16), stats via DETERMINISTIC tree:
// 16-lane shfl_xor allreduce -> per-wave partials in LDS [8][64] ->
// threads 0..63 fold 8 partials sequentially -> mu/rsig. Pass 2 reads the
// values from REGISTERS (acc reused), not global.
template<int K>
__global__ __launch_bounds__(512)
void gemm_ln(const __hip_bfloat16* __restrict__ A,
             const __hip_bfloat16* __restrict__ W,
             const float* __restrict__ bias, const float* __restrict__ res,
             float* __restrict__ outF,
             const float* __restrict__ lnG, const float* __restrict__ lnB,
             __hip_bfloat16* __restrict__ hOut,
             int M, int mtiles, int doLN)
{
    constexpr int ASZ = 64 * 128;           // 8KB
    constexpr int WSZ = 256 * 128;          // 32KB
    __shared__ char lds[2 * ASZ + 2 * WSZ];

    int orig = blockIdx.x;
    int q = mtiles >> 3, r = mtiles & 7;
    int xcd = orig & 7, loc = orig >> 3;
    int wgid = (xcd < r ? xcd * (q + 1) : r * (q + 1) + (xcd - r) * q) + loc;
    int bm = wgid * 64;

    int tid = threadIdx.x;
    int lane = tid & 63;
    int wc = tid >> 6;                       // 0..7 (1x8 wave grid)
    int l15 = lane & 15, l4 = lane >> 4;

    f32x4 acc[4][2] = {};

    auto stage = [&](int t, int b) {
        int k0 = t * 64;
        char* Asb = lds + b * ASZ;
        char* Wsb = lds + 2 * ASZ + b * WSZ;
        {                                            // A: 1 load/thread
            int chunk = tid;
            int rr = chunk >> 3;
            int sc = (chunk & 7) ^ (rr & 7);
            int grow = min(bm + rr, M - 1);          // clamp: ALWAYS issue
            gload_lds16((const char*)A + ((size_t)grow * K + k0) * 2 + sc * 16,
                        Asb + chunk * 16);
        }
#pragma unroll
        for (int it = 0; it < 4; ++it) {             // W: 4 loads/thread
            int chunk = it * 512 + tid;
            int rr = chunk >> 3;                     // 0..255
            int sc = (chunk & 7) ^ (rr & 7);
            gload_lds16((const char*)W + ((size_t)rr * K + k0) * 2 + sc * 16,
                        Wsb + chunk * 16);
        }
    };

    int nk = K >> 6;
    stage(0, 0);
    for (int t = 0; t < nk; ++t) {
        int cur = t & 1;
        if (t + 1 < nk) {
            stage(t + 1, cur ^ 1);
            asm volatile("s_waitcnt vmcnt(5)" ::: "memory");
        } else {
            asm volatile("s_waitcnt vmcnt(0)" ::: "memory");
        }
        __builtin_amdgcn_s_barrier();
        char* As = lds + cur * ASZ;
        char* Ws = lds + 2 * ASZ + cur * WSZ;
#pragma unroll
        for (int s = 0; s < 2; ++s) {
            bf16frag af[4], bfr[2];
            int kb = s * 64 + (l4 << 4);
#pragma unroll
            for (int m = 0; m < 4; ++m) {
                int ar = m * 16 + l15;               // rows 0..63
                af[m] = *(const bf16frag*)(As + ar * 128 + (kb ^ ((ar & 7) << 4)));
            }
#pragma unroll
            for (int n = 0; n < 2; ++n) {
                int br = wc * 32 + n * 16 + l15;     // 0..255
                bfr[n] = *(const bf16frag*)(Ws + br * 128 + (kb ^ ((br & 7) << 4)));
            }
#pragma unroll
            for (int m = 0; m < 4; ++m)
#pragma unroll
                for (int n = 0; n < 2; ++n)
                    acc[m][n] = __builtin_amdgcn_mfma_f32_16x16x32_bf16(
                        af[m], bfr[n], acc[m][n], 0, 0, 0);
        }
        __builtin_amdgcn_s_barrier();
    }

    // ---- LDS scratch for stats (A-buf region is dead now) ----
    float* wsum = (float*)lds;               // [8][64]
    float* wsq  = wsum + 512;                // [8][64]
    float* muA  = wsq + 512;                 // [64]
    float* rsA  = muA + 64;                  // [64]

    // ---- pass 1: residual add, fp32 out, values back into acc, tree stats --
#pragma unroll
    for (int m = 0; m < 4; ++m)
#pragma unroll
        for (int rr = 0; rr < 4; ++rr) {
            int lrow = m * 16 + (l4 << 2) + rr;
            int grow = bm + lrow;
            float v0 = 0.f, v1 = 0.f;
            if (grow < M) {
                int c0 = wc * 32 + l15;
                int c1 = c0 + 16;
                v0 = acc[m][0][rr] + bias[c0] + res[(size_t)grow * 256 + c0];
                v1 = acc[m][1][rr] + bias[c1] + res[(size_t)grow * 256 + c1];
                outF[(size_t)grow * 256 + c0] = v0;
                outF[(size_t)grow * 256 + c1] = v1;
                acc[m][0][rr] = v0;
                acc[m][1][rr] = v1;
            }
            if (doLN) {
                float ps = v0 + v1;
                float pq = v0 * v0 + v1 * v1;
#pragma unroll
                for (int off = 8; off; off >>= 1) {
                    ps += __shfl_xor(ps, off);
                    pq += __shfl_xor(pq, off);
                }
                if (l15 == 0) {
                    wsum[wc * 64 + lrow] = ps;
                    wsq[wc * 64 + lrow] = pq;
                }
            }
        }

    if (!doLN) return;
    __syncthreads();
    if (tid < 64) {
        float s = 0.f, q2 = 0.f;
#pragma unroll
        for (int w8 = 0; w8 < 8; ++w8) {
            s += wsum[w8 * 64 + tid];
            q2 += wsq[w8 * 64 + tid];
        }
        float m_ = s * (1.f / 256.f);
        float va = q2 * (1.f / 256.f) - m_ * m_;
        muA[tid] = m_;
        rsA[tid] = rsqrtf(va + 1e-5f);
    }
    __syncthreads();

    // ---- pass 2: LN from registers -> bf16 h ----
#pragma unroll
    for (int m = 0; m < 4; ++m)
#pragma unroll
        for (int rr = 0; rr < 4; ++rr) {
            int lrow = m * 16 + (l4 << 2) + rr;
            int grow = bm + lrow;
            if (grow < M) {
                float mu = muA[lrow], rs = rsA[lrow];
                int c0 = wc * 32 + l15;
                int c1 = c0 + 16;
                hOut[(size_t)grow * 256 + c0] =
                    __float2bfloat16((acc[m][0][rr] - mu) * rs * lnG[c0] + lnB[c0]);
                hOut[(size_t)grow * 256 + c1] =
                    __float2bfloat16((acc[m][1][rr] - mu) * rs * lnG[c1] + lnB[c1]);
            }
        }
}

// ---------------- CSR build: count + hierarchical scan + scatter ------------
__global__ void count_kernel(const int* __restrict__ dst, int* __restrict__ count, int E)
{
    int e = blockIdx.x * blockDim.x + threadIdx.x;
    if (e < E) atomicAdd(&count[dst[e]], 1);
}

__global__ __launch_bounds__(1024)
void scanA_kernel(const int* __restrict__ count, int* __restrict__ rowptr,
                  int* __restrict__ bsum, int N)
{
    __shared__ int sdata[1024];
    int b = blockIdx.x, t = threadIdx.x;
    int idx = b * 1024 + t;
    int v = (idx < N) ? count[idx] : 0;
    sdata[t] = v;
    __syncthreads();
    for (int off = 1; off < 1024; off <<= 1) {
        int add = (t >= off) ? sdata[t - off] : 0;
        __syncthreads();
        sdata[t] += add;
        __syncthreads();
    }
    if (idx < N) rowptr[idx + 1] = sdata[t];
    if (t == 1023) bsum[b] = sdata[1023];
}

__global__ void scanB_kernel(int* __restrict__ bsum, int nb)
{
    int t = threadIdx.x;
    int v = (t < nb) ? bsum[t] : 0;
#pragma unroll
    for (int off = 1; off < 64; off <<= 1) {
        int u = __shfl_up(v, off);
        if (t >= off) v += u;
    }
    if (t < nb) bsum[t] = v;
}

__global__ __launch_bounds__(1024)
void scanC_kernel(int* __restrict__ rowptr, const int* __restrict__ bsum, int N)
{
    int b = blockIdx.x, t = threadIdx.x;
    int idx = b * 1024 + t;
    if (idx == 0) rowptr[0] = 0;
    if (idx < N && b > 0) rowptr[idx + 1] += bsum[b - 1];
}

__global__ void scatter_kernel(const int* __restrict__ src, const int* __restrict__ dst,
                               const int* __restrict__ rowptr, int* __restrict__ cursor,
                               int* __restrict__ srcperm, int E)
{
    int e = blockIdx.x * blockDim.x + threadIdx.x;
    if (e < E) {
        int d = dst[e];
        int pos = rowptr[d] + atomicAdd(&cursor[d], 1);
        srcperm[pos] = src[e];
    }
}

// ---------------- Attention: wave/node, cross-chunk K prefetch --------------
__global__ __launch_bounds__(256)
void attn_kernel(const __hip_bfloat16* __restrict__ qkv, const int* __restrict__ rowptr,
                 const int* __restrict__ srcperm, __hip_bfloat16* __restrict__ agg,
                 int N)
{
    int wid = (blockIdx.x * 256 + threadIdx.x) >> 6;   // node index
    if (wid >= N) return;
    int lane = threadIdx.x & 63;
    int h = lane >> 4, u = lane & 15;
    int i = wid;
    int beg = rowptr[i], deg = rowptr[i + 1] - beg;
    const short* base = (const short*)qkv;
    const float scale = 0.17677669529663687f; // 1/sqrt(32)

    bf16frag qf[4];
    const short* qr = base + (size_t)i * QKVC + h * 32;
#pragma unroll
    for (int c = 0; c < 4; ++c) qf[c] = *(const bf16frag*)(qr + c * 8);

    float m_run = -3.4e38f, d_run = 0.f;
    float accx = 0.f, accy = 0.f;

    int j = (u < deg) ? srcperm[beg + u] : i;
    bf16frag kf[4];
    {
        const short* kr = base + (size_t)j * QKVC + 128 + h * 32;
#pragma unroll
        for (int c = 0; c < 4; ++c) kf[c] = *(const bf16frag*)(kr + c * 8);
    }

    for (int c0 = 0; c0 < deg; c0 += 16) {
        int cn = min(16, deg - c0);
        bool valid = (u < cn);

        int nxt = c0 + 16 + u;
        int jn = (nxt < deg) ? srcperm[beg + nxt] : i;

        float dot = 0.f;
#pragma unroll
        for (int c = 0; c < 4; ++c)
#pragma unroll
            for (int e = 0; e < 8; ++e)
                dot += b2f(qf[c][e]) * b2f(kf[c][e]);
        float alpha = valid ? dot * scale : -3.4e38f;

        float cm = alpha;
#pragma unroll
        for (int off = 8; off; off >>= 1) cm = fmaxf(cm, __shfl_xor(cm, off));
        float m_new = fmaxf(m_run, cm);
        float rescale = __expf(m_run - m_new);
        float w = valid ? __expf(alpha - m_new) : 0.f;
        float dsum = w;
#pragma unroll
        for (int off = 8; off; off >>= 1) dsum += __shfl_xor(dsum, off);
        d_run = d_run * rescale + dsum;
        m_run = m_new;
        accx *= rescale;
        accy *= rescale;

        bf16frag kfn[4];
        {
            const short* krn = base + (size_t)jn * QKVC + 128 + h * 32;
#pragma unroll
            for (int c = 0; c < 4; ++c) kfn[c] = *(const bf16frag*)(krn + c * 8);
        }

        float wes[16];
        unsigned vws[16];
#pragma unroll
        for (int e = 0; e < 16; ++e) {
            wes[e] = __shfl(w, h * 16 + e);
            int je = __shfl(j, h * 16 + e);        // invalid slots -> row i
            vws[e] = *(const unsigned*)(base + (size_t)je * QKVC + 256 + h * 32 + u * 2);
        }
#pragma unroll
        for (int e = 0; e < 16; ++e) {
            accx += wes[e] * b2f((short)(vws[e] & 0xffff));
            accy += wes[e] * b2f((short)(vws[e] >> 16));
        }
        j = jn;
#pragma unroll
        for (int c = 0; c < 4; ++c) kf[c] = kfn[c];
    }

    float inv = 1.f / (d_run + 1e-16f);
    __hip_bfloat16* outp = agg + (size_t)i * INNERC + h * 32 + u * 2;
    outp[0] = __float2bfloat16(accx * inv);
    outp[1] = __float2bfloat16(accy * inv);
}

// ---------------- Launch ----------------
extern "C" void kernel_launch(void* const* d_in, const int* in_sizes, int n_in,
                              void* d_out, int out_size, void* d_ws, size_t ws_size,
                              hipStream_t stream)
{
    const float* x    = (const float*)d_in[0];
    const int*   ei   = (const int*)  d_in[1];
    const float* ln1g = (const float*)d_in[2];
    const float* ln1b = (const float*)d_in[3];
    const float* wq   = (const float*)d_in[4];
    const float* bq   = (const float*)d_in[5];
    const float* wk   = (const float*)d_in[6];
    const float* bk   = (const float*)d_in[7];
    const float* wv   = (const float*)d_in[8];
    const float* bv   = (const float*)d_in[9];
    const float* wo   = (const float*)d_in[10];
    const float* bo   = (const float*)d_in[11];
    const float* ln2g = (const float*)d_in[12];
    const float* ln2b = (const float*)d_in[13];
    const float* w1   = (const float*)d_in[14];
    const float* b1   = (const float*)d_in[15];
    const float* w2   = (const float*)d_in[16];
    const float* b2   = (const float*)d_in[17];

    const int N = in_sizes[0] / DIMC;   // 20000
    const int E = in_sizes[1] / 2;      // 320000
    const int* srcIdx = ei;
    const int* dstIdx = ei + E;

    char* p = (char*)d_ws;
    auto alloc = [&](size_t bytes) {
        char* r = p;
        p += (bytes + 255) & ~(size_t)255;
        return r;
    };
    float*          xbuf   = (float*)alloc((size_t)N * DIMC * 4);
    __hip_bfloat16* h      = (__hip_bfloat16*)alloc((size_t)N * DIMC * 2);
    __hip_bfloat16* qkv    = (__hip_bfloat16*)alloc((size_t)N * QKVC * 2);
    __hip_bfloat16* agg    = (__hip_bfloat16*)alloc((size_t)N * INNERC * 2);
    __hip_bfloat16* u      = (__hip_bfloat16*)alloc((size_t)N * 1024 * 2);
    int*            rowptr = (int*)alloc((size_t)(N + 1) * 4);
    int*            cnt    = (int*)alloc((size_t)N * 4);
    int*            bsum   = (int*)alloc((size_t)64 * 4);
    int*            srcperm= (int*)alloc((size_t)E * 4);
    __hip_bfloat16* wqkvB  = (__hip_bfloat16*)alloc((size_t)4 * QKVC * DIMC * 2);
    float*          bqkvF  = (float*)alloc((size_t)4 * QKVC * 4);
    __hip_bfloat16* woB    = (__hip_bfloat16*)alloc((size_t)4 * DIMC * INNERC * 2);
    __hip_bfloat16* w1B    = (__hip_bfloat16*)alloc((size_t)4 * 1024 * DIMC * 2);
    __hip_bfloat16* w2B    = (__hip_bfloat16*)alloc((size_t)4 * DIMC * 1024 * 2);

    // Weight conversion (per-call, deterministic)
    packqkv_kernel<<<4 * QKVC, 256, 0, stream>>>(wq, wk, wv, bq, bk, bv, wqkvB, bqkvF);
    {
        int n = 4 * DIMC * INNERC;
        f2b_kernel<<<(n / 4 + 255) / 256, 256, 0, stream>>>(wo, woB, n);
        n = 4 * 1024 * DIMC;
        f2b_kernel<<<(n / 4 + 255) / 256, 256, 0, stream>>>(w1, w1B, n);
        f2b_kernel<<<(n / 4 + 255) / 256, 256, 0, stream>>>(w2, w2B, n);
    }

    // CSR build (hierarchical scan)
    int nb = (N + 1023) / 1024;     // 20
    hipMemsetAsync(cnt, 0, (size_t)N * 4, stream);
    count_kernel<<<(E + 255) / 256, 256, 0, stream>>>(dstIdx, cnt, E);
    scanA_kernel<<<nb, 1024, 0, stream>>>(cnt, rowptr, bsum, N);
    scanB_kernel<<<1, 64, 0, stream>>>(bsum, nb);
    scanC_kernel<<<nb, 1024, 0, stream>>>(rowptr, bsum, N);
    hipMemsetAsync(cnt, 0, (size_t)N * 4, stream);
    scatter_kernel<<<(E + 255) / 256, 256, 0, stream>>>(srcIdx, dstIdx, rowptr, cnt, srcperm, E);

    int mt = (N + 127) / 128;        // 157
    int mt64 = (N + 63) / 64;        // 313
    int attnBlocks = (N * 64 + 255) / 256;
    for (int l = 0; l < 4; ++l) {
        const float* xin = (l == 0) ? x : xbuf;
        if (l == 0)
            ln_kernel<<<(N + 3) / 4, 256, 0, stream>>>(x, ln1g, ln1b, h, N);
        // QKV: OUT=384 -> 3 ntiles, 471 blocks
        mfma_gemm<0><<<mt * 3, 512, 0, stream>>>(
            h, wqkvB + (size_t)l * QKVC * DIMC, bqkvF + l * QKVC, nullptr,
            qkv, N, DIMC, QKVC, mt, 3);
        attn_kernel<<<attnBlocks, 256, 0, stream>>>(qkv, rowptr, srcperm, agg, N);
        // out-proj + residual + LN2 -> xbuf (fp32) and h (bf16)
        gemm_ln<128><<<mt64, 512, 0, stream>>>(
            agg, woB + (size_t)l * DIMC * INNERC, bo + l * DIMC, xin,
            xbuf, ln2g + l * DIMC, ln2b + l * DIMC, h, N, mt64, 1);
        // FF1: OUT=1024 -> 8 ntiles, 1256 blocks
        mfma_gemm<1><<<mt * 8, 512, 0, stream>>>(
            h, w1B + (size_t)l * 1024 * DIMC, b1 + l * 1024, nullptr,
            u, N, DIMC, 1024, mt, 8);
        float* xout = (l == 3) ? (float*)d_out : xbuf;
        // FF2 + residual + next-layer LN1 -> xout (fp32) and h (bf16, if l<3)
        gemm_ln<1024><<<mt64, 512, 0, stream>>>(
            u, w2B + (size_t)l * DIMC * 1024, b2 + l * DIMC, xbuf,
            xout, ln1g + (size_t)(l + 1 < 4 ? l + 1 : 0) * DIMC,
            ln1b + (size_t)(l + 1 < 4 ? l + 1 : 0) * DIMC, h, N, mt64,
            (l < 3) ? 1 : 0);
    }
}

// Round 16
// 554.068 us; speedup vs baseline: 1.0283x; 1.0283x over previous
//
#include <hip/hip_runtime.h>
#include <hip/hip_bf16.h>
#include <math.h>

#define DIMC 256
#define INNERC 128
#define HEADSC 4
#define DHC 32
#define QKVC 384

typedef __attribute__((ext_vector_type(8))) short bf16frag;   // 8 bf16 = 4 VGPRs
typedef __attribute__((ext_vector_type(4))) float f32x4;

__device__ __forceinline__ float gelu_exact(float x) {
    return 0.5f * x * (1.0f + erff(x * 0.70710678118654752f));
}

__device__ __forceinline__ float b2f(short s) {
    return __uint_as_float(((unsigned)(unsigned short)s) << 16);
}

__device__ __forceinline__ void gload_lds16(const void* g, void* l) {
    __builtin_amdgcn_global_load_lds(
        (const __attribute__((address_space(1))) void*)g,
        (__attribute__((address_space(3))) void*)l, 16, 0, 0);
}

// ---------------- LayerNorm: one WAVE per row, no barriers ----------------
__global__ __launch_bounds__(256)
void ln_kernel(const float* __restrict__ x, const float* __restrict__ g,
               const float* __restrict__ b, __hip_bfloat16* __restrict__ out,
               int N)
{
    int row = blockIdx.x * 4 + (threadIdx.x >> 6);
    if (row >= N) return;
    int lane = threadIdx.x & 63;
    float4 v = *(const float4*)(x + (size_t)row * DIMC + lane * 4);
    float s = v.x + v.y + v.z + v.w;
    float s2 = v.x * v.x + v.y * v.y + v.z * v.z + v.w * v.w;
#pragma unroll
    for (int off = 32; off; off >>= 1) {
        s += __shfl_xor(s, off);
        s2 += __shfl_xor(s2, off);
    }
    float mean = s * (1.f / DIMC);
    float var = s2 * (1.f / DIMC) - mean * mean;
    float rs = rsqrtf(var + 1e-5f);
    float4 gv = *(const float4*)(g + lane * 4);
    float4 bv = *(const float4*)(b + lane * 4);
    __hip_bfloat16 o[4];
    o[0] = __float2bfloat16((v.x - mean) * rs * gv.x + bv.x);
    o[1] = __float2bfloat16((v.y - mean) * rs * gv.y + bv.y);
    o[2] = __float2bfloat16((v.z - mean) * rs * gv.z + bv.z);
    o[3] = __float2bfloat16((v.w - mean) * rs * gv.w + bv.w);
    *(short4*)(out + (size_t)row * DIMC + lane * 4) = *(short4*)o;
}

// ---------------- fp32 -> bf16 convert (n % 4 == 0) ----------------
__global__ void f2b_kernel(const float* __restrict__ src,
                           __hip_bfloat16* __restrict__ dst, int n)
{
    int i = (blockIdx.x * blockDim.x + threadIdx.x) * 4;
    if (i < n) {
        float4 v = *(const float4*)(src + i);
        dst[i + 0] = __float2bfloat16(v.x);
        dst[i + 1] = __float2bfloat16(v.y);
        dst[i + 2] = __float2bfloat16(v.z);
        dst[i + 3] = __float2bfloat16(v.w);
    }
}

// ---------------- pack wq/wk/wv -> wqkv bf16 [4][384][256], biases [4][384] ----
__global__ __launch_bounds__(256)
void packqkv_kernel(const float* __restrict__ wq, const float* __restrict__ wk,
                    const float* __restrict__ wv, const float* __restrict__ bq,
                    const float* __restrict__ bk, const float* __restrict__ bv,
                    __hip_bfloat16* __restrict__ wqkv, float* __restrict__ bqkv)
{
    int row = blockIdx.x;                 // 0 .. 4*384-1
    int l = row / QKVC, c = row % QKVC;
    int which = c >> 7, cc = c & 127;
    const float* srcw = which == 0 ? wq : which == 1 ? wk : wv;
    const float* srcb = which == 0 ? bq : which == 1 ? bk : bv;
    srcw += ((size_t)l * INNERC + cc) * DIMC;
    wqkv[(size_t)row * DIMC + threadIdx.x] = __float2bfloat16(srcw[threadIdx.x]);
    if (threadIdx.x == 0) bqkv[row] = srcb[l * INNERC + cc];
}

// ---------------- MFMA GEMM v6: v5 + hoisted staging addresses --------------
// C[M][OUT] = A[M][K] @ W[OUT][K]^T + bias.  BM=128, BK=64, BN=128.
// 8 waves (2x4), wave tile 64x32, dbuf + counted vmcnt(4) (unchanged).
// NEW: per-thread global source pointers & LDS dest offsets precomputed ONCE;
// source pointers advance by 128B per K-step (kills per-step VALU addr calc).
// EPI: 0 = bias -> bf16; 1 = bias+gelu -> bf16; 2 = bias+res -> fp32.
template<int EPI>
__global__ __launch_bounds__(512)
void mfma_gemm(const __hip_bfloat16* __restrict__ A,
               const __hip_bfloat16* __restrict__ W,
               const float* __restrict__ bias, const float* __restrict__ res,
               void* __restrict__ Cout, int M, int K, int OUT,
               int mtiles, int ntiles)
{
    constexpr int ASZ = 128 * 128;          // one A buf (16KB)
    constexpr int WSZ = 128 * 128;          // one W buf (16KB)
    __shared__ char lds[2 * ASZ + 2 * WSZ];

    int nwg = mtiles * ntiles;
    int orig = blockIdx.x;
    int q = nwg >> 3, r = nwg & 7;
    int xcd = orig & 7, loc = orig >> 3;
    int wgid = (xcd < r ? xcd * (q + 1) : r * (q + 1) + (xcd - r) * q) + loc;
    int bm = (wgid / ntiles) * 128;
    int bn = (wgid % ntiles) * 128;

    int tid = threadIdx.x;
    int lane = tid & 63;
    int w = tid >> 6;                        // 0..7
    int wr = w >> 2, wc = w & 3;             // 2 x 4 wave grid
    int l15 = lane & 15, l4 = lane >> 4;

    // ---- hoisted staging addresses (computed once) ----
    const char* aSrc[2];
    const char* wSrc[2];
    int dOff[2];
#pragma unroll
    for (int it = 0; it < 2; ++it) {
        int chunk = it * 512 + tid;
        int rr = chunk >> 3;
        int sc = (chunk & 7) ^ (rr & 7);
        int grow = min(bm + rr, M - 1);      // clamp: ALWAYS issue
        aSrc[it] = (const char*)A + ((size_t)grow * K) * 2 + sc * 16;
        wSrc[it] = (const char*)W + ((size_t)(bn + rr) * K) * 2 + sc * 16;
        dOff[it] = chunk * 16;
    }

    f32x4 acc[4][2] = {};

    auto stage = [&](int b) {               // stages current pointers, advances
        char* Asb = lds + b * ASZ;
        char* Wsb = lds + 2 * ASZ + b * WSZ;
#pragma unroll
        for (int it = 0; it < 2; ++it) {
            gload_lds16(aSrc[it], Asb + dOff[it]);
            aSrc[it] += 128;                 // 64 bf16 = one K-step
        }
#pragma unroll
        for (int it = 0; it < 2; ++it) {
            gload_lds16(wSrc[it], Wsb + dOff[it]);
            wSrc[it] += 128;
        }
    };

    int nk = K >> 6;
    stage(0);
    for (int t = 0; t < nk; ++t) {
        int cur = t & 1;
        if (t + 1 < nk) {
            stage(cur ^ 1);                              // prefetch next tile
            asm volatile("s_waitcnt vmcnt(4)" ::: "memory");   // tile t only
        } else {
            asm volatile("s_waitcnt vmcnt(0)" ::: "memory");
        }
        __builtin_amdgcn_s_barrier();                    // tile t visible
        char* As = lds + cur * ASZ;
        char* Ws = lds + 2 * ASZ + cur * WSZ;
#pragma unroll
        for (int s = 0; s < 2; ++s) {
            bf16frag af[4], bfr[2];
            int kb = s * 64 + (l4 << 4);
#pragma unroll
            for (int m = 0; m < 4; ++m) {
                int ar = wr * 64 + m * 16 + l15;
                af[m] = *(const bf16frag*)(As + ar * 128 + (kb ^ ((ar & 7) << 4)));
            }
#pragma unroll
            for (int n = 0; n < 2; ++n) {
                int br = wc * 32 + n * 16 + l15;
                bfr[n] = *(const bf16frag*)(Ws + br * 128 + (kb ^ ((br & 7) << 4)));
            }
#pragma unroll
            for (int m = 0; m < 4; ++m)
#pragma unroll
                for (int n = 0; n < 2; ++n)
                    acc[m][n] = __builtin_amdgcn_mfma_f32_16x16x32_bf16(
                        af[m], bfr[n], acc[m][n], 0, 0, 0);
        }
        __builtin_amdgcn_s_barrier();                    // WAR on buf
    }

#pragma unroll
    for (int m = 0; m < 4; ++m)
#pragma unroll
        for (int rr = 0; rr < 4; ++rr) {
            int grow = bm + wr * 64 + m * 16 + (l4 << 2) + rr;
            if (grow < M) {
#pragma unroll
                for (int n = 0; n < 2; ++n) {
                    int gcol = bn + wc * 32 + n * 16 + l15;
                    float val = acc[m][n][rr] + bias[gcol];
                    if (EPI == 1) val = gelu_exact(val);
                    if (EPI == 2) {
                        val += res[(size_t)grow * OUT + gcol];
                        ((float*)Cout)[(size_t)grow * OUT + gcol] = val;
                    } else {
                        ((__hip_bfloat16*)Cout)[(size_t)grow * OUT + gcol] =
                            __float2bfloat16(val);
                    }
                }
            }
        }
}

// ---------------- CSR build: count + hierarchical scan + scatter ------------
__global__ void count_kernel(const int* __restrict__ dst, int* __restrict__ count, int E)
{
    int e = blockIdx.x * blockDim.x + threadIdx.x;
    if (e < E) atomicAdd(&count[dst[e]], 1);
}

__global__ __launch_bounds__(1024)
void scanA_kernel(const int* __restrict__ count, int* __restrict__ rowptr,
                  int* __restrict__ bsum, int N)
{
    __shared__ int sdata[1024];
    int b = blockIdx.x, t = threadIdx.x;
    int idx = b * 1024 + t;
    int v = (idx < N) ? count[idx] : 0;
    sdata[t] = v;
    __syncthreads();
    for (int off = 1; off < 1024; off <<= 1) {
        int add = (t >= off) ? sdata[t - off] : 0;
        __syncthreads();
        sdata[t] += add;
        __syncthreads();
    }
    if (idx < N) rowptr[idx + 1] = sdata[t];
    if (t == 1023) bsum[b] = sdata[1023];
}

__global__ void scanB_kernel(int* __restrict__ bsum, int nb)
{
    int t = threadIdx.x;
    int v = (t < nb) ? bsum[t] : 0;
#pragma unroll
    for (int off = 1; off < 64; off <<= 1) {
        int u = __shfl_up(v, off);
        if (t >= off) v += u;
    }
    if (t < nb) bsum[t] = v;
}

__global__ __launch_bounds__(1024)
void scanC_kernel(int* __restrict__ rowptr, const int* __restrict__ bsum, int N)
{
    int b = blockIdx.x, t = threadIdx.x;
    int idx = b * 1024 + t;
    if (idx == 0) rowptr[0] = 0;
    if (idx < N && b > 0) rowptr[idx + 1] += bsum[b - 1];
}

__global__ void scatter_kernel(const int* __restrict__ src, const int* __restrict__ dst,
                               const int* __restrict__ rowptr, int* __restrict__ cursor,
                               int* __restrict__ srcperm, int E)
{
    int e = blockIdx.x * blockDim.x + threadIdx.x;
    if (e < E) {
        int d = dst[e];
        int pos = rowptr[d] + atomicAdd(&cursor[d], 1);
        srcperm[pos] = src[e];
    }
}

// ---------------- Attention: wave/node, cross-chunk K prefetch --------------
__global__ __launch_bounds__(256)
void attn_kernel(const __hip_bfloat16* __restrict__ qkv, const int* __restrict__ rowptr,
                 const int* __restrict__ srcperm, __hip_bfloat16* __restrict__ agg,
                 int N)
{
    int wid = (blockIdx.x * 256 + threadIdx.x) >> 6;   // node index
    if (wid >= N) return;
    int lane = threadIdx.x & 63;
    int h = lane >> 4, u = lane & 15;
    int i = wid;
    int beg = rowptr[i], deg = rowptr[i + 1] - beg;
    const short* base = (const short*)qkv;
    const float scale = 0.17677669529663687f; // 1/sqrt(32)

    bf16frag qf[4];
    const short* qr = base + (size_t)i * QKVC + h * 32;
#pragma unroll
    for (int c = 0; c < 4; ++c) qf[c] = *(const bf16frag*)(qr + c * 8);

    float m_run = -3.4e38f, d_run = 0.f;
    float accx = 0.f, accy = 0.f;

    int j = (u < deg) ? srcperm[beg + u] : i;
    bf16frag kf[4];
    {
        const short* kr = base + (size_t)j * QKVC + 128 + h * 32;
#pragma unroll
        for (int c = 0; c < 4; ++c) kf[c] = *(const bf16frag*)(kr + c * 8);
    }

    for (int c0 = 0; c0 < deg; c0 += 16) {
        int cn = min(16, deg - c0);
        bool valid = (u < cn);

        int nxt = c0 + 16 + u;
        int jn = (nxt < deg) ? srcperm[beg + nxt] : i;

        float dot = 0.f;
#pragma unroll
        for (int c = 0; c < 4; ++c)
#pragma unroll
            for (int e = 0; e < 8; ++e)
                dot += b2f(qf[c][e]) * b2f(kf[c][e]);
        float alpha = valid ? dot * scale : -3.4e38f;

        float cm = alpha;
#pragma unroll
        for (int off = 8; off; off >>= 1) cm = fmaxf(cm, __shfl_xor(cm, off));
        float m_new = fmaxf(m_run, cm);
        float rescale = __expf(m_run - m_new);
        float w = valid ? __expf(alpha - m_new) : 0.f;
        float dsum = w;
#pragma unroll
        for (int off = 8; off; off >>= 1) dsum += __shfl_xor(dsum, off);
        d_run = d_run * rescale + dsum;
        m_run = m_new;
        accx *= rescale;
        accy *= rescale;

        bf16frag kfn[4];
        {
            const short* krn = base + (size_t)jn * QKVC + 128 + h * 32;
#pragma unroll
            for (int c = 0; c < 4; ++c) kfn[c] = *(const bf16frag*)(krn + c * 8);
        }

        float wes[16];
        unsigned vws[16];
#pragma unroll
        for (int e = 0; e < 16; ++e) {
            wes[e] = __shfl(w, h * 16 + e);
            int je = __shfl(j, h * 16 + e);        // invalid slots -> row i
            vws[e] = *(const unsigned*)(base + (size_t)je * QKVC + 256 + h * 32 + u * 2);
        }
#pragma unroll
        for (int e = 0; e < 16; ++e) {
            accx += wes[e] * b2f((short)(vws[e] & 0xffff));
            accy += wes[e] * b2f((short)(vws[e] >> 16));
        }
        j = jn;
#pragma unroll
        for (int c = 0; c < 4; ++c) kf[c] = kfn[c];
    }

    float inv = 1.f / (d_run + 1e-16f);
    __hip_bfloat16* outp = agg + (size_t)i * INNERC + h * 32 + u * 2;
    outp[0] = __float2bfloat16(accx * inv);
    outp[1] = __float2bfloat16(accy * inv);
}

// ---------------- Launch ----------------
extern "C" void kernel_launch(void* const* d_in, const int* in_sizes, int n_in,
                              void* d_out, int out_size, void* d_ws, size_t ws_size,
                              hipStream_t stream)
{
    const float* x    = (const float*)d_in[0];
    const int*   ei   = (const int*)  d_in[1];
    const float* ln1g = (const float*)d_in[2];
    const float* ln1b = (const float*)d_in[3];
    const float* wq   = (const float*)d_in[4];
    const float* bq   = (const float*)d_in[5];
    const float* wk   = (const float*)d_in[6];
    const float* bk   = (const float*)d_in[7];
    const float* wv   = (const float*)d_in[8];
    const float* bv   = (const float*)d_in[9];
    const float* wo   = (const float*)d_in[10];
    const float* bo   = (const float*)d_in[11];
    const float* ln2g = (const float*)d_in[12];
    const float* ln2b = (const float*)d_in[13];
    const float* w1   = (const float*)d_in[14];
    const float* b1   = (const float*)d_in[15];
    const float* w2   = (const float*)d_in[16];
    const float* b2   = (const float*)d_in[17];

    const int N = in_sizes[0] / DIMC;   // 20000
    const int E = in_sizes[1] / 2;      // 320000
    const int* srcIdx = ei;
    const int* dstIdx = ei + E;

    char* p = (char*)d_ws;
    auto alloc = [&](size_t bytes) {
        char* r = p;
        p += (bytes + 255) & ~(size_t)255;
        return r;
    };
    float*          xbuf   = (float*)alloc((size_t)N * DIMC * 4);
    __hip_bfloat16* h      = (__hip_bfloat16*)alloc((size_t)N * DIMC * 2);
    __hip_bfloat16* qkv    = (__hip_bfloat16*)alloc((size_t)N * QKVC * 2);
    __hip_bfloat16* agg    = (__hip_bfloat16*)alloc((size_t)N * INNERC * 2);
    __hip_bfloat16* u      = (__hip_bfloat16*)alloc((size_t)N * 1024 * 2);
    int*            rowptr = (int*)alloc((size_t)(N + 1) * 4);
    int*            cnt    = (int*)alloc((size_t)N * 4);
    int*            bsum   = (int*)alloc((size_t)64 * 4);
    int*            srcperm= (int*)alloc((size_t)E * 4);
    __hip_bfloat16* wqkvB  = (__hip_bfloat16*)alloc((size_t)4 * QKVC * DIMC * 2);
    float*          bqkvF  = (float*)alloc((size_t)4 * QKVC * 4);
    __hip_bfloat16* woB    = (__hip_bfloat16*)alloc((size_t)4 * DIMC * INNERC * 2);
    __hip_bfloat16* w1B    = (__hip_bfloat16*)alloc((size_t)4 * 1024 * DIMC * 2);
    __hip_bfloat16* w2B    = (__hip_bfloat16*)alloc((size_t)4 * DIMC * 1024 * 2);

    // Weight conversion (per-call, deterministic)
    packqkv_kernel<<<4 * QKVC, 256, 0, stream>>>(wq, wk, wv, bq, bk, bv, wqkvB, bqkvF);
    {
        int n = 4 * DIMC * INNERC;
        f2b_kernel<<<(n / 4 + 255) / 256, 256, 0, stream>>>(wo, woB, n);
        n = 4 * 1024 * DIMC;
        f2b_kernel<<<(n / 4 + 255) / 256, 256, 0, stream>>>(w1, w1B, n);
        f2b_kernel<<<(n / 4 + 255) / 256, 256, 0, stream>>>(w2, w2B, n);
    }

    // CSR build (hierarchical scan)
    int nb = (N + 1023) / 1024;     // 20
    hipMemsetAsync(cnt, 0, (size_t)N * 4, stream);
    count_kernel<<<(E + 255) / 256, 256, 0, stream>>>(dstIdx, cnt, E);
    scanA_kernel<<<nb, 1024, 0, stream>>>(cnt, rowptr, bsum, N);
    scanB_kernel<<<1, 64, 0, stream>>>(bsum, nb);
    scanC_kernel<<<nb, 1024, 0, stream>>>(rowptr, bsum, N);
    hipMemsetAsync(cnt, 0, (size_t)N * 4, stream);
    scatter_kernel<<<(E + 255) / 256, 256, 0, stream>>>(srcIdx, dstIdx, rowptr, cnt, srcperm, E);

    int mt = (N + 127) / 128;        // 157
    int lnBlocks = (N + 3) / 4;      // 5000
    int attnBlocks = (N * 64 + 255) / 256;
    for (int l = 0; l < 4; ++l) {
        const float* xin = (l == 0) ? x : xbuf;
        ln_kernel<<<lnBlocks, 256, 0, stream>>>(xin, ln1g + l * DIMC, ln1b + l * DIMC, h, N);
        // QKV: OUT=384 -> 3 ntiles, 471 blocks
        mfma_gemm<0><<<mt * 3, 512, 0, stream>>>(
            h, wqkvB + (size_t)l * QKVC * DIMC, bqkvF + l * QKVC, nullptr,
            qkv, N, DIMC, QKVC, mt, 3);
        attn_kernel<<<attnBlocks, 256, 0, stream>>>(qkv, rowptr, srcperm, agg, N);
        // out-proj: OUT=256, K=128 -> 314 blocks
        mfma_gemm<2><<<mt * 2, 512, 0, stream>>>(
            agg, woB + (size_t)l * DIMC * INNERC, bo + l * DIMC, xin,
            xbuf, N, INNERC, DIMC, mt, 2);
        ln_kernel<<<lnBlocks, 256, 0, stream>>>(xbuf, ln2g + l * DIMC, ln2b + l * DIMC, h, N);
        // FF1: OUT=1024 -> 8 ntiles, 1256 blocks
        mfma_gemm<1><<<mt * 8, 512, 0, stream>>>(
            h, w1B + (size_t)l * 1024 * DIMC, b1 + l * 1024, nullptr,
            u, N, DIMC, 1024, mt, 8);
        float* xout = (l == 3) ? (float*)d_out : xbuf;
        // FF2: OUT=256, K=1024 -> 314 blocks, 16 K-steps (pipeline fills)
        mfma_gemm<2><<<mt * 2, 512, 0, stream>>>(
            u, w2B + (size_t)l * DIMC * 1024, b2 + l * DIMC, xbuf,
            xout, N, 1024, DIMC, mt, 2);
    }
}

// Round 17
// 509.608 us; speedup vs baseline: 1.1180x; 1.0872x over previous
//
#include <hip/hip_runtime.h>
#include <hip/hip_bf16.h>
#include <math.h>

#define DIMC 256
#define INNERC 128
#define HEADSC 4
#define DHC 32
#define QKVC 384

typedef __attribute__((ext_vector_type(8))) short bf16frag;   // 8 bf16 = 4 VGPRs
typedef __attribute__((ext_vector_type(4))) float f32x4;

__device__ __forceinline__ float gelu_exact(float x) {
    return 0.5f * x * (1.0f + erff(x * 0.70710678118654752f));
}

__device__ __forceinline__ float b2f(short s) {
    return __uint_as_float(((unsigned)(unsigned short)s) << 16);
}

__device__ __forceinline__ void gload_lds16(const void* g, void* l) {
    __builtin_amdgcn_global_load_lds(
        (const __attribute__((address_space(1))) void*)g,
        (__attribute__((address_space(3))) void*)l, 16, 0, 0);
}

// ---------------- LayerNorm: one WAVE per row, no barriers ----------------
__global__ __launch_bounds__(256)
void ln_kernel(const float* __restrict__ x, const float* __restrict__ g,
               const float* __restrict__ b, __hip_bfloat16* __restrict__ out,
               int N)
{
    int row = blockIdx.x * 4 + (threadIdx.x >> 6);
    if (row >= N) return;
    int lane = threadIdx.x & 63;
    float4 v = *(const float4*)(x + (size_t)row * DIMC + lane * 4);
    float s = v.x + v.y + v.z + v.w;
    float s2 = v.x * v.x + v.y * v.y + v.z * v.z + v.w * v.w;
#pragma unroll
    for (int off = 32; off; off >>= 1) {
        s += __shfl_xor(s, off);
        s2 += __shfl_xor(s2, off);
    }
    float mean = s * (1.f / DIMC);
    float var = s2 * (1.f / DIMC) - mean * mean;
    float rs = rsqrtf(var + 1e-5f);
    float4 gv = *(const float4*)(g + lane * 4);
    float4 bv = *(const float4*)(b + lane * 4);
    __hip_bfloat16 o[4];
    o[0] = __float2bfloat16((v.x - mean) * rs * gv.x + bv.x);
    o[1] = __float2bfloat16((v.y - mean) * rs * gv.y + bv.y);
    o[2] = __float2bfloat16((v.z - mean) * rs * gv.z + bv.z);
    o[3] = __float2bfloat16((v.w - mean) * rs * gv.w + bv.w);
    *(short4*)(out + (size_t)row * DIMC + lane * 4) = *(short4*)o;
}

// ---------------- fp32 -> bf16 convert (n % 4 == 0) ----------------
__global__ void f2b_kernel(const float* __restrict__ src,
                           __hip_bfloat16* __restrict__ dst, int n)
{
    int i = (blockIdx.x * blockDim.x + threadIdx.x) * 4;
    if (i < n) {
        float4 v = *(const float4*)(src + i);
        dst[i + 0] = __float2bfloat16(v.x);
        dst[i + 1] = __float2bfloat16(v.y);
        dst[i + 2] = __float2bfloat16(v.z);
        dst[i + 3] = __float2bfloat16(v.w);
    }
}

// ---------------- pack wq/wk/wv -> wqkv bf16 [4][384][256], biases [4][384] ----
__global__ __launch_bounds__(256)
void packqkv_kernel(const float* __restrict__ wq, const float* __restrict__ wk,
                    const float* __restrict__ wv, const float* __restrict__ bq,
                    const float* __restrict__ bk, const float* __restrict__ bv,
                    __hip_bfloat16* __restrict__ wqkv, float* __restrict__ bqkv)
{
    int row = blockIdx.x;                 // 0 .. 4*384-1
    int l = row / QKVC, c = row % QKVC;
    int which = c >> 7, cc = c & 127;
    const float* srcw = which == 0 ? wq : which == 1 ? wk : wv;
    const float* srcb = which == 0 ? bq : which == 1 ? bk : bv;
    srcw += ((size_t)l * INNERC + cc) * DIMC;
    wqkv[(size_t)row * DIMC + threadIdx.x] = __float2bfloat16(srcw[threadIdx.x]);
    if (threadIdx.x == 0) bqkv[row] = srcb[l * INNERC + cc];
}

// ---------------- MFMA GEMM v7: v6 + LDS-staged coalesced epilogue ----------
// C[M][OUT] = A[M][K] @ W[OUT][K]^T + bias.  BM=128, BK=64, BN=128.
// 8 waves (2x4), dbuf + counted vmcnt(4), hoisted staging pointers.
// NEW: epilogue stages the 128x128 fp32 tile in LDS ([128][132] pad) and
// writes fully-coalesced 256B (bf16) / 512B (fp32) row segments; EPI=2's
// res reads are also coalesced float4.
// EPI: 0 = bias -> bf16; 1 = bias+gelu -> bf16; 2 = bias+res -> fp32.
template<int EPI>
__global__ __launch_bounds__(512)
void mfma_gemm(const __hip_bfloat16* __restrict__ A,
               const __hip_bfloat16* __restrict__ W,
               const float* __restrict__ bias, const float* __restrict__ res,
               void* __restrict__ Cout, int M, int K, int OUT,
               int mtiles, int ntiles)
{
    constexpr int ASZ = 128 * 128;          // one A buf (16KB)
    constexpr int WSZ = 128 * 128;          // one W buf (16KB)
    constexpr int EPAD = 132;               // fp32 tile row stride (floats)
    __shared__ char lds[128 * EPAD * 4];    // 67584B >= 2*ASZ+2*WSZ (65536)

    int nwg = mtiles * ntiles;
    int orig = blockIdx.x;
    int q = nwg >> 3, r = nwg & 7;
    int xcd = orig & 7, loc = orig >> 3;
    int wgid = (xcd < r ? xcd * (q + 1) : r * (q + 1) + (xcd - r) * q) + loc;
    int bm = (wgid / ntiles) * 128;
    int bn = (wgid % ntiles) * 128;

    int tid = threadIdx.x;
    int lane = tid & 63;
    int w = tid >> 6;                        // 0..7
    int wr = w >> 2, wc = w & 3;             // 2 x 4 wave grid
    int l15 = lane & 15, l4 = lane >> 4;

    // ---- hoisted staging addresses (computed once) ----
    const char* aSrc[2];
    const char* wSrc[2];
    int dOff[2];
#pragma unroll
    for (int it = 0; it < 2; ++it) {
        int chunk = it * 512 + tid;
        int rr = chunk >> 3;
        int sc = (chunk & 7) ^ (rr & 7);
        int grow = min(bm + rr, M - 1);      // clamp: ALWAYS issue
        aSrc[it] = (const char*)A + ((size_t)grow * K) * 2 + sc * 16;
        wSrc[it] = (const char*)W + ((size_t)(bn + rr) * K) * 2 + sc * 16;
        dOff[it] = chunk * 16;
    }

    f32x4 acc[4][2] = {};

    auto stage = [&](int b) {
        char* Asb = lds + b * ASZ;
        char* Wsb = lds + 2 * ASZ + b * WSZ;
#pragma unroll
        for (int it = 0; it < 2; ++it) {
            gload_lds16(aSrc[it], Asb + dOff[it]);
            aSrc[it] += 128;                 // 64 bf16 = one K-step
        }
#pragma unroll
        for (int it = 0; it < 2; ++it) {
            gload_lds16(wSrc[it], Wsb + dOff[it]);
            wSrc[it] += 128;
        }
    };

    int nk = K >> 6;
    stage(0);
    for (int t = 0; t < nk; ++t) {
        int cur = t & 1;
        if (t + 1 < nk) {
            stage(cur ^ 1);                              // prefetch next tile
            asm volatile("s_waitcnt vmcnt(4)" ::: "memory");   // tile t only
        } else {
            asm volatile("s_waitcnt vmcnt(0)" ::: "memory");
        }
        __builtin_amdgcn_s_barrier();                    // tile t visible
        char* As = lds + cur * ASZ;
        char* Ws = lds + 2 * ASZ + cur * WSZ;
#pragma unroll
        for (int s = 0; s < 2; ++s) {
            bf16frag af[4], bfr[2];
            int kb = s * 64 + (l4 << 4);
#pragma unroll
            for (int m = 0; m < 4; ++m) {
                int ar = wr * 64 + m * 16 + l15;
                af[m] = *(const bf16frag*)(As + ar * 128 + (kb ^ ((ar & 7) << 4)));
            }
#pragma unroll
            for (int n = 0; n < 2; ++n) {
                int br = wc * 32 + n * 16 + l15;
                bfr[n] = *(const bf16frag*)(Ws + br * 128 + (kb ^ ((br & 7) << 4)));
            }
#pragma unroll
            for (int m = 0; m < 4; ++m)
#pragma unroll
                for (int n = 0; n < 2; ++n)
                    acc[m][n] = __builtin_amdgcn_mfma_f32_16x16x32_bf16(
                        af[m], bfr[n], acc[m][n], 0, 0, 0);
        }
        __builtin_amdgcn_s_barrier();                    // WAR on buf
    }

    // ---- epilogue: stage fp32 tile to LDS, then coalesced writes ----
    float* tile = (float*)lds;               // [128][EPAD]
    __syncthreads();                          // all LDS K-loop reads done
#pragma unroll
    for (int m = 0; m < 4; ++m)
#pragma unroll
        for (int rr = 0; rr < 4; ++rr) {
            int lrow = wr * 64 + m * 16 + (l4 << 2) + rr;
#pragma unroll
            for (int n = 0; n < 2; ++n) {
                int lcol = wc * 32 + n * 16 + l15;
                float val = acc[m][n][rr] + bias[bn + lcol];
                if (EPI == 1) val = gelu_exact(val);
                tile[lrow * EPAD + lcol] = val;
            }
        }
    __syncthreads();

    if (EPI == 2) {
        // fp32 out + res: 32 threads/row (512B), 16 rows/pass, 8 passes
        int rp = tid >> 5, c4 = (tid & 31) * 4;
        float* outF = (float*)Cout;
#pragma unroll
        for (int pass = 0; pass < 8; ++pass) {
            int lrow = pass * 16 + rp;
            int grow = bm + lrow;
            if (grow < M) {
                float4 v = *(float4*)&tile[lrow * EPAD + c4];
                const float4 rv = *(const float4*)&res[(size_t)grow * OUT + bn + c4];
                v.x += rv.x; v.y += rv.y; v.z += rv.z; v.w += rv.w;
                *(float4*)&outF[(size_t)grow * OUT + bn + c4] = v;
            }
        }
    } else {
        // bf16 out: 32 threads/row (256B), 16 rows/pass, 8 passes
        int rp = tid >> 5, c4 = (tid & 31) * 4;
        __hip_bfloat16* outB = (__hip_bfloat16*)Cout;
#pragma unroll
        for (int pass = 0; pass < 8; ++pass) {
            int lrow = pass * 16 + rp;
            int grow = bm + lrow;
            if (grow < M) {
                float4 v = *(float4*)&tile[lrow * EPAD + c4];
                __hip_bfloat16 o[4];
                o[0] = __float2bfloat16(v.x);
                o[1] = __float2bfloat16(v.y);
                o[2] = __float2bfloat16(v.z);
                o[3] = __float2bfloat16(v.w);
                *(short4*)&outB[(size_t)grow * OUT + bn + c4] = *(short4*)o;
            }
        }
    }
}

// ---------------- CSR build: count + hierarchical scan + scatter ------------
__global__ void count_kernel(const int* __restrict__ dst, int* __restrict__ count, int E)
{
    int e = blockIdx.x * blockDim.x + threadIdx.x;
    if (e < E) atomicAdd(&count[dst[e]], 1);
}

__global__ __launch_bounds__(1024)
void scanA_kernel(const int* __restrict__ count, int* __restrict__ rowptr,
                  int* __restrict__ bsum, int N)
{
    __shared__ int sdata[1024];
    int b = blockIdx.x, t = threadIdx.x;
    int idx = b * 1024 + t;
    int v = (idx < N) ? count[idx] : 0;
    sdata[t] = v;
    __syncthreads();
    for (int off = 1; off < 1024; off <<= 1) {
        int add = (t >= off) ? sdata[t - off] : 0;
        __syncthreads();
        sdata[t] += add;
        __syncthreads();
    }
    if (idx < N) rowptr[idx + 1] = sdata[t];
    if (t == 1023) bsum[b] = sdata[1023];
}

__global__ void scanB_kernel(int* __restrict__ bsum, int nb)
{
    int t = threadIdx.x;
    int v = (t < nb) ? bsum[t] : 0;
#pragma unroll
    for (int off = 1; off < 64; off <<= 1) {
        int u = __shfl_up(v, off);
        if (t >= off) v += u;
    }
    if (t < nb) bsum[t] = v;
}

__global__ __launch_bounds__(1024)
void scanC_kernel(int* __restrict__ rowptr, const int* __restrict__ bsum, int N)
{
    int b = blockIdx.x, t = threadIdx.x;
    int idx = b * 1024 + t;
    if (idx == 0) rowptr[0] = 0;
    if (idx < N && b > 0) rowptr[idx + 1] += bsum[b - 1];
}

__global__ void scatter_kernel(const int* __restrict__ src, const int* __restrict__ dst,
                               const int* __restrict__ rowptr, int* __restrict__ cursor,
                               int* __restrict__ srcperm, int E)
{
    int e = blockIdx.x * blockDim.x + threadIdx.x;
    if (e < E) {
        int d = dst[e];
        int pos = rowptr[d] + atomicAdd(&cursor[d], 1);
        srcperm[pos] = src[e];
    }
}

// ---------------- Attention: wave/node, cross-chunk K prefetch --------------
__global__ __launch_bounds__(256)
void attn_kernel(const __hip_bfloat16* __restrict__ qkv, const int* __restrict__ rowptr,
                 const int* __restrict__ srcperm, __hip_bfloat16* __restrict__ agg,
                 int N)
{
    int wid = (blockIdx.x * 256 + threadIdx.x) >> 6;   // node index
    if (wid >= N) return;
    int lane = threadIdx.x & 63;
    int h = lane >> 4, u = lane & 15;
    int i = wid;
    int beg = rowptr[i], deg = rowptr[i + 1] - beg;
    const short* base = (const short*)qkv;
    const float scale = 0.17677669529663687f; // 1/sqrt(32)

    bf16frag qf[4];
    const short* qr = base + (size_t)i * QKVC + h * 32;
#pragma unroll
    for (int c = 0; c < 4; ++c) qf[c] = *(const bf16frag*)(qr + c * 8);

    float m_run = -3.4e38f, d_run = 0.f;
    float accx = 0.f, accy = 0.f;

    int j = (u < deg) ? srcperm[beg + u] : i;
    bf16frag kf[4];
    {
        const short* kr = base + (size_t)j * QKVC + 128 + h * 32;
#pragma unroll
        for (int c = 0; c < 4; ++c) kf[c] = *(const bf16frag*)(kr + c * 8);
    }

    for (int c0 = 0; c0 < deg; c0 += 16) {
        int cn = min(16, deg - c0);
        bool valid = (u < cn);

        int nxt = c0 + 16 + u;
        int jn = (nxt < deg) ? srcperm[beg + nxt] : i;

        float dot = 0.f;
#pragma unroll
        for (int c = 0; c < 4; ++c)
#pragma unroll
            for (int e = 0; e < 8; ++e)
                dot += b2f(qf[c][e]) * b2f(kf[c][e]);
        float alpha = valid ? dot * scale : -3.4e38f;

        float cm = alpha;
#pragma unroll
        for (int off = 8; off; off >>= 1) cm = fmaxf(cm, __shfl_xor(cm, off));
        float m_new = fmaxf(m_run, cm);
        float rescale = __expf(m_run - m_new);
        float w = valid ? __expf(alpha - m_new) : 0.f;
        float dsum = w;
#pragma unroll
        for (int off = 8; off; off >>= 1) dsum += __shfl_xor(dsum, off);
        d_run = d_run * rescale + dsum;
        m_run = m_new;
        accx *= rescale;
        accy *= rescale;

        bf16frag kfn[4];
        {
            const short* krn = base + (size_t)jn * QKVC + 128 + h * 32;
#pragma unroll
            for (int c = 0; c < 4; ++c) kfn[c] = *(const bf16frag*)(krn + c * 8);
        }

        float wes[16];
        unsigned vws[16];
#pragma unroll
        for (int e = 0; e < 16; ++e) {
            wes[e] = __shfl(w, h * 16 + e);
            int je = __shfl(j, h * 16 + e);        // invalid slots -> row i
            vws[e] = *(const unsigned*)(base + (size_t)je * QKVC + 256 + h * 32 + u * 2);
        }
#pragma unroll
        for (int e = 0; e < 16; ++e) {
            accx += wes[e] * b2f((short)(vws[e] & 0xffff));
            accy += wes[e] * b2f((short)(vws[e] >> 16));
        }
        j = jn;
#pragma unroll
        for (int c = 0; c < 4; ++c) kf[c] = kfn[c];
    }

    float inv = 1.f / (d_run + 1e-16f);
    __hip_bfloat16* outp = agg + (size_t)i * INNERC + h * 32 + u * 2;
    outp[0] = __float2bfloat16(accx * inv);
    outp[1] = __float2bfloat16(accy * inv);
}

// ---------------- Launch ----------------
extern "C" void kernel_launch(void* const* d_in, const int* in_sizes, int n_in,
                              void* d_out, int out_size, void* d_ws, size_t ws_size,
                              hipStream_t stream)
{
    const float* x    = (const float*)d_in[0];
    const int*   ei   = (const int*)  d_in[1];
    const float* ln1g = (const float*)d_in[2];
    const float* ln1b = (const float*)d_in[3];
    const float* wq   = (const float*)d_in[4];
    const float* bq   = (const float*)d_in[5];
    const float* wk   = (const float*)d_in[6];
    const float* bk   = (const float*)d_in[7];
    const float* wv   = (const float*)d_in[8];
    const float* bv   = (const float*)d_in[9];
    const float* wo   = (const float*)d_in[10];
    const float* bo   = (const float*)d_in[11];
    const float* ln2g = (const float*)d_in[12];
    const float* ln2b = (const float*)d_in[13];
    const float* w1   = (const float*)d_in[14];
    const float* b1   = (const float*)d_in[15];
    const float* w2   = (const float*)d_in[16];
    const float* b2   = (const float*)d_in[17];

    const int N = in_sizes[0] / DIMC;   // 20000
    const int E = in_sizes[1] / 2;      // 320000
    const int* srcIdx = ei;
    const int* dstIdx = ei + E;

    char* p = (char*)d_ws;
    auto alloc = [&](size_t bytes) {
        char* r = p;
        p += (bytes + 255) & ~(size_t)255;
        return r;
    };
    float*          xbuf   = (float*)alloc((size_t)N * DIMC * 4);
    __hip_bfloat16* h      = (__hip_bfloat16*)alloc((size_t)N * DIMC * 2);
    __hip_bfloat16* qkv    = (__hip_bfloat16*)alloc((size_t)N * QKVC * 2);
    __hip_bfloat16* agg    = (__hip_bfloat16*)alloc((size_t)N * INNERC * 2);
    __hip_bfloat16* u      = (__hip_bfloat16*)alloc((size_t)N * 1024 * 2);
    int*            rowptr = (int*)alloc((size_t)(N + 1) * 4);
    int*            cnt    = (int*)alloc((size_t)N * 4);
    int*            bsum   = (int*)alloc((size_t)64 * 4);
    int*            srcperm= (int*)alloc((size_t)E * 4);
    __hip_bfloat16* wqkvB  = (__hip_bfloat16*)alloc((size_t)4 * QKVC * DIMC * 2);
    float*          bqkvF  = (float*)alloc((size_t)4 * QKVC * 4);
    __hip_bfloat16* woB    = (__hip_bfloat16*)alloc((size_t)4 * DIMC * INNERC * 2);
    __hip_bfloat16* w1B    = (__hip_bfloat16*)alloc((size_t)4 * 1024 * DIMC * 2);
    __hip_bfloat16* w2B    = (__hip_bfloat16*)alloc((size_t)4 * DIMC * 1024 * 2);

    // Weight conversion (per-call, deterministic)
    packqkv_kernel<<<4 * QKVC, 256, 0, stream>>>(wq, wk, wv, bq, bk, bv, wqkvB, bqkvF);
    {
        int n = 4 * DIMC * INNERC;
        f2b_kernel<<<(n / 4 + 255) / 256, 256, 0, stream>>>(wo, woB, n);
        n = 4 * 1024 * DIMC;
        f2b_kernel<<<(n / 4 + 255) / 256, 256, 0, stream>>>(w1, w1B, n);
        f2b_kernel<<<(n / 4 + 255) / 256, 256, 0, stream>>>(w2, w2B, n);
    }

    // CSR build (hierarchical scan)
    int nb = (N + 1023) / 1024;     // 20
    hipMemsetAsync(cnt, 0, (size_t)N * 4, stream);
    count_kernel<<<(E + 255) / 256, 256, 0, stream>>>(dstIdx, cnt, E);
    scanA_kernel<<<nb, 1024, 0, stream>>>(cnt, rowptr, bsum, N);
    scanB_kernel<<<1, 64, 0, stream>>>(bsum, nb);
    scanC_kernel<<<nb, 1024, 0, stream>>>(rowptr, bsum, N);
    hipMemsetAsync(cnt, 0, (size_t)N * 4, stream);
    scatter_kernel<<<(E + 255) / 256, 256, 0, stream>>>(srcIdx, dstIdx, rowptr, cnt, srcperm, E);

    int mt = (N + 127) / 128;        // 157
    int lnBlocks = (N + 3) / 4;      // 5000
    int attnBlocks = (N * 64 + 255) / 256;
    for (int l = 0; l < 4; ++l) {
        const float* xin = (l == 0) ? x : xbuf;
        ln_kernel<<<lnBlocks, 256, 0, stream>>>(xin, ln1g + l * DIMC, ln1b + l * DIMC, h, N);
        // QKV: OUT=384 -> 3 ntiles, 471 blocks
        mfma_gemm<0><<<mt * 3, 512, 0, stream>>>(
            h, wqkvB + (size_t)l * QKVC * DIMC, bqkvF + l * QKVC, nullptr,
            qkv, N, DIMC, QKVC, mt, 3);
        attn_kernel<<<attnBlocks, 256, 0, stream>>>(qkv, rowptr, srcperm, agg, N);
        // out-proj: OUT=256, K=128 -> 314 blocks
        mfma_gemm<2><<<mt * 2, 512, 0, stream>>>(
            agg, woB + (size_t)l * DIMC * INNERC, bo + l * DIMC, xin,
            xbuf, N, INNERC, DIMC, mt, 2);
        ln_kernel<<<lnBlocks, 256, 0, stream>>>(xbuf, ln2g + l * DIMC, ln2b + l * DIMC, h, N);
        // FF1: OUT=1024 -> 8 ntiles, 1256 blocks
        mfma_gemm<1><<<mt * 8, 512, 0, stream>>>(
            h, w1B + (size_t)l * 1024 * DIMC, b1 + l * 1024, nullptr,
            u, N, DIMC, 1024, mt, 8);
        float* xout = (l == 3) ? (float*)d_out : xbuf;
        // FF2: OUT=256, K=1024 -> 314 blocks, 16 K-steps (pipeline fills)
        mfma_gemm<2><<<mt * 2, 512, 0, stream>>>(
            u, w2B + (size_t)l * DIMC * 1024, b2 + l * DIMC, xbuf,
            xout, N, 1024, DIMC, mt, 2);
    }
}

// Round 18
// 509.286 us; speedup vs baseline: 1.1187x; 1.0006x over previous
//
#include <hip/hip_runtime.h>
#include <hip/hip_bf16.h>
#include <math.h>

#define DIMC 256
#define INNERC 128
#define HEADSC 4
#define DHC 32
#define QKVC 384

typedef __attribute__((ext_vector_type(8))) short bf16frag;   // 8 bf16 = 4 VGPRs
typedef __attribute__((ext_vector_type(4))) float f32x4;

__device__ __forceinline__ float gelu_exact(float x) {
    return 0.5f * x * (1.0f + erff(x * 0.70710678118654752f));
}

__device__ __forceinline__ float b2f(short s) {
    return __uint_as_float(((unsigned)(unsigned short)s) << 16);
}

__device__ __forceinline__ void gload_lds16(const void* g, void* l) {
    __builtin_amdgcn_global_load_lds(
        (const __attribute__((address_space(1))) void*)g,
        (__attribute__((address_space(3))) void*)l, 16, 0, 0);
}

// ---------------- LayerNorm: one WAVE per row, no barriers ----------------
__global__ __launch_bounds__(256)
void ln_kernel(const float* __restrict__ x, const float* __restrict__ g,
               const float* __restrict__ b, __hip_bfloat16* __restrict__ out,
               int N)
{
    int row = blockIdx.x * 4 + (threadIdx.x >> 6);
    if (row >= N) return;
    int lane = threadIdx.x & 63;
    float4 v = *(const float4*)(x + (size_t)row * DIMC + lane * 4);
    float s = v.x + v.y + v.z + v.w;
    float s2 = v.x * v.x + v.y * v.y + v.z * v.z + v.w * v.w;
#pragma unroll
    for (int off = 32; off; off >>= 1) {
        s += __shfl_xor(s, off);
        s2 += __shfl_xor(s2, off);
    }
    float mean = s * (1.f / DIMC);
    float var = s2 * (1.f / DIMC) - mean * mean;
    float rs = rsqrtf(var + 1e-5f);
    float4 gv = *(const float4*)(g + lane * 4);
    float4 bv = *(const float4*)(b + lane * 4);
    __hip_bfloat16 o[4];
    o[0] = __float2bfloat16((v.x - mean) * rs * gv.x + bv.x);
    o[1] = __float2bfloat16((v.y - mean) * rs * gv.y + bv.y);
    o[2] = __float2bfloat16((v.z - mean) * rs * gv.z + bv.z);
    o[3] = __float2bfloat16((v.w - mean) * rs * gv.w + bv.w);
    *(short4*)(out + (size_t)row * DIMC + lane * 4) = *(short4*)o;
}

// ---------------- fp32 -> bf16 convert (n % 4 == 0) ----------------
__global__ void f2b_kernel(const float* __restrict__ src,
                           __hip_bfloat16* __restrict__ dst, int n)
{
    int i = (blockIdx.x * blockDim.x + threadIdx.x) * 4;
    if (i < n) {
        float4 v = *(const float4*)(src + i);
        dst[i + 0] = __float2bfloat16(v.x);
        dst[i + 1] = __float2bfloat16(v.y);
        dst[i + 2] = __float2bfloat16(v.z);
        dst[i + 3] = __float2bfloat16(v.w);
    }
}

// ---------------- pack wq/wk/wv -> wqkv bf16 [4][384][256], biases [4][384] ----
__global__ __launch_bounds__(256)
void packqkv_kernel(const float* __restrict__ wq, const float* __restrict__ wk,
                    const float* __restrict__ wv, const float* __restrict__ bq,
                    const float* __restrict__ bk, const float* __restrict__ bv,
                    __hip_bfloat16* __restrict__ wqkv, float* __restrict__ bqkv)
{
    int row = blockIdx.x;                 // 0 .. 4*384-1
    int l = row / QKVC, c = row % QKVC;
    int which = c >> 7, cc = c & 127;
    const float* srcw = which == 0 ? wq : which == 1 ? wk : wv;
    const float* srcb = which == 0 ? bq : which == 1 ? bk : bv;
    srcw += ((size_t)l * INNERC + cc) * DIMC;
    wqkv[(size_t)row * DIMC + threadIdx.x] = __float2bfloat16(srcw[threadIdx.x]);
    if (threadIdx.x == 0) bqkv[row] = srcb[l * INNERC + cc];
}

// ---------------- MFMA GEMM v8: templated BM (128 or 64), BN=128 ------------
// C[M][OUT] = A[M][K] @ W[OUT][K]^T + bias.  BK=64, 512 thr, 8 waves 2x4.
// BM=128: wave tile 64x32 (acc 4x2), LDS 64K -> 2 blocks/CU. (FF1)
// BM=64 : wave tile 32x32 (acc 2x2), LDS 48K -> 3 blocks/CU, grid 2x denser.
//         (QKV / OP / FF2 — fixes block-count starvation on 256 CUs)
// dbuf + counted vmcnt keeps prefetch in flight across raw barriers (m218);
// hoisted staging pointers; T5 setprio around MFMA cluster; LDS-staged
// coalesced epilogue (v7).
// EPI: 0 = bias -> bf16; 1 = bias+gelu -> bf16; 2 = bias+res -> fp32.
template<int EPI, int BM>
__global__ __launch_bounds__(512)
void mfma_gemm(const __hip_bfloat16* __restrict__ A,
               const __hip_bfloat16* __restrict__ W,
               const float* __restrict__ bias, const float* __restrict__ res,
               void* __restrict__ Cout, int M, int K, int OUT,
               int mtiles, int ntiles)
{
    constexpr int ASZ = BM * 128;           // one A buf
    constexpr int WSZ = 128 * 128;          // one W buf (16KB)
    constexpr int EPAD = 132;               // fp32 tile row stride (floats)
    constexpr int KSZ = 2 * ASZ + 2 * WSZ;
    constexpr int ESZ = BM * EPAD * 4;
    constexpr int LDSZ = (KSZ > ESZ) ? KSZ : ESZ;
    constexpr int MFR = BM / 32;            // acc row-frags per wave (4 or 2)
    constexpr int ALD = (BM * 8) / 512;     // A loads/thread (2 or 1)
    __shared__ char lds[LDSZ];

    int nwg = mtiles * ntiles;
    int orig = blockIdx.x;
    int q = nwg >> 3, r = nwg & 7;
    int xcd = orig & 7, loc = orig >> 3;
    int wgid = (xcd < r ? xcd * (q + 1) : r * (q + 1) + (xcd - r) * q) + loc;
    int bm = (wgid / ntiles) * BM;
    int bn = (wgid % ntiles) * 128;

    int tid = threadIdx.x;
    int lane = tid & 63;
    int w = tid >> 6;                        // 0..7
    int wr = w >> 2, wc = w & 3;             // 2 x 4 wave grid
    int l15 = lane & 15, l4 = lane >> 4;

    // ---- hoisted staging addresses (computed once) ----
    const char* aSrc[ALD];
    const char* wSrc[2];
    int aOff[ALD], wOff[2];
#pragma unroll
    for (int it = 0; it < ALD; ++it) {
        int chunk = it * 512 + tid;
        int rr = chunk >> 3;
        int sc = (chunk & 7) ^ (rr & 7);
        int grow = min(bm + rr, M - 1);      // clamp: ALWAYS issue
        aSrc[it] = (const char*)A + ((size_t)grow * K) * 2 + sc * 16;
        aOff[it] = chunk * 16;
    }
#pragma unroll
    for (int it = 0; it < 2; ++it) {
        int chunk = it * 512 + tid;
        int rr = chunk >> 3;
        int sc = (chunk & 7) ^ (rr & 7);
        wSrc[it] = (const char*)W + ((size_t)(bn + rr) * K) * 2 + sc * 16;
        wOff[it] = chunk * 16;
    }

    f32x4 acc[MFR][2] = {};

    auto stage = [&](int b) {
        char* Asb = lds + b * ASZ;
        char* Wsb = lds + 2 * ASZ + b * WSZ;
#pragma unroll
        for (int it = 0; it < ALD; ++it) {
            gload_lds16(aSrc[it], Asb + aOff[it]);
            aSrc[it] += 128;                 // 64 bf16 = one K-step
        }
#pragma unroll
        for (int it = 0; it < 2; ++it) {
            gload_lds16(wSrc[it], Wsb + wOff[it]);
            wSrc[it] += 128;
        }
    };

    int nk = K >> 6;
    stage(0);
    for (int t = 0; t < nk; ++t) {
        int cur = t & 1;
        if (t + 1 < nk) {
            stage(cur ^ 1);                              // prefetch next tile
            if constexpr (BM == 128)
                asm volatile("s_waitcnt vmcnt(4)" ::: "memory");  // tile t only
            else
                asm volatile("s_waitcnt vmcnt(3)" ::: "memory");
        } else {
            asm volatile("s_waitcnt vmcnt(0)" ::: "memory");
        }
        __builtin_amdgcn_s_barrier();                    // tile t visible
        char* As = lds + cur * ASZ;
        char* Ws = lds + 2 * ASZ + cur * WSZ;
#pragma unroll
        for (int s = 0; s < 2; ++s) {
            bf16frag af[MFR], bfr[2];
            int kb = s * 64 + (l4 << 4);
#pragma unroll
            for (int m = 0; m < MFR; ++m) {
                int ar = wr * (BM / 2) + m * 16 + l15;
                af[m] = *(const bf16frag*)(As + ar * 128 + (kb ^ ((ar & 7) << 4)));
            }
#pragma unroll
            for (int n = 0; n < 2; ++n) {
                int br = wc * 32 + n * 16 + l15;
                bfr[n] = *(const bf16frag*)(Ws + br * 128 + (kb ^ ((br & 7) << 4)));
            }
            __builtin_amdgcn_s_setprio(1);
#pragma unroll
            for (int m = 0; m < MFR; ++m)
#pragma unroll
                for (int n = 0; n < 2; ++n)
                    acc[m][n] = __builtin_amdgcn_mfma_f32_16x16x32_bf16(
                        af[m], bfr[n], acc[m][n], 0, 0, 0);
            __builtin_amdgcn_s_setprio(0);
        }
        __builtin_amdgcn_s_barrier();                    // WAR on buf
    }

    // ---- epilogue: stage fp32 tile to LDS, then coalesced writes ----
    float* tile = (float*)lds;               // [BM][EPAD]
    __syncthreads();                          // all LDS K-loop reads done
#pragma unroll
    for (int m = 0; m < MFR; ++m)
#pragma unroll
        for (int rr = 0; rr < 4; ++rr) {
            int lrow = wr * (BM / 2) + m * 16 + (l4 << 2) + rr;
#pragma unroll
            for (int n = 0; n < 2; ++n) {
                int lcol = wc * 32 + n * 16 + l15;
                float val = acc[m][n][rr] + bias[bn + lcol];
                if (EPI == 1) val = gelu_exact(val);
                tile[lrow * EPAD + lcol] = val;
            }
        }
    __syncthreads();

    if (EPI == 2) {
        // fp32 out + res: 32 threads/row (512B), 16 rows/pass
        int rp = tid >> 5, c4 = (tid & 31) * 4;
        float* outF = (float*)Cout;
#pragma unroll
        for (int pass = 0; pass < BM / 16; ++pass) {
            int lrow = pass * 16 + rp;
            int grow = bm + lrow;
            if (grow < M) {
                float4 v = *(float4*)&tile[lrow * EPAD + c4];
                const float4 rv = *(const float4*)&res[(size_t)grow * OUT + bn + c4];
                v.x += rv.x; v.y += rv.y; v.z += rv.z; v.w += rv.w;
                *(float4*)&outF[(size_t)grow * OUT + bn + c4] = v;
            }
        }
    } else {
        // bf16 out: 32 threads/row (256B), 16 rows/pass
        int rp = tid >> 5, c4 = (tid & 31) * 4;
        __hip_bfloat16* outB = (__hip_bfloat16*)Cout;
#pragma unroll
        for (int pass = 0; pass < BM / 16; ++pass) {
            int lrow = pass * 16 + rp;
            int grow = bm + lrow;
            if (grow < M) {
                float4 v = *(float4*)&tile[lrow * EPAD + c4];
                __hip_bfloat16 o[4];
                o[0] = __float2bfloat16(v.x);
                o[1] = __float2bfloat16(v.y);
                o[2] = __float2bfloat16(v.z);
                o[3] = __float2bfloat16(v.w);
                *(short4*)&outB[(size_t)grow * OUT + bn + c4] = *(short4*)o;
            }
        }
    }
}

// ---------------- CSR build: count + hierarchical scan + scatter ------------
__global__ void count_kernel(const int* __restrict__ dst, int* __restrict__ count, int E)
{
    int e = blockIdx.x * blockDim.x + threadIdx.x;
    if (e < E) atomicAdd(&count[dst[e]], 1);
}

__global__ __launch_bounds__(1024)
void scanA_kernel(const int* __restrict__ count, int* __restrict__ rowptr,
                  int* __restrict__ bsum, int N)
{
    __shared__ int sdata[1024];
    int b = blockIdx.x, t = threadIdx.x;
    int idx = b * 1024 + t;
    int v = (idx < N) ? count[idx] : 0;
    sdata[t] = v;
    __syncthreads();
    for (int off = 1; off < 1024; off <<= 1) {
        int add = (t >= off) ? sdata[t - off] : 0;
        __syncthreads();
        sdata[t] += add;
        __syncthreads();
    }
    if (idx < N) rowptr[idx + 1] = sdata[t];
    if (t == 1023) bsum[b] = sdata[1023];
}

__global__ void scanB_kernel(int* __restrict__ bsum, int nb)
{
    int t = threadIdx.x;
    int v = (t < nb) ? bsum[t] : 0;
#pragma unroll
    for (int off = 1; off < 64; off <<= 1) {
        int u = __shfl_up(v, off);
        if (t >= off) v += u;
    }
    if (t < nb) bsum[t] = v;
}

__global__ __launch_bounds__(1024)
void scanC_kernel(int* __restrict__ rowptr, const int* __restrict__ bsum, int N)
{
    int b = blockIdx.x, t = threadIdx.x;
    int idx = b * 1024 + t;
    if (idx == 0) rowptr[0] = 0;
    if (idx < N && b > 0) rowptr[idx + 1] += bsum[b - 1];
}

__global__ void scatter_kernel(const int* __restrict__ src, const int* __restrict__ dst,
                               const int* __restrict__ rowptr, int* __restrict__ cursor,
                               int* __restrict__ srcperm, int E)
{
    int e = blockIdx.x * blockDim.x + threadIdx.x;
    if (e < E) {
        int d = dst[e];
        int pos = rowptr[d] + atomicAdd(&cursor[d], 1);
        srcperm[pos] = src[e];
    }
}

// ---------------- Attention: wave/node, cross-chunk K prefetch --------------
__global__ __launch_bounds__(256)
void attn_kernel(const __hip_bfloat16* __restrict__ qkv, const int* __restrict__ rowptr,
                 const int* __restrict__ srcperm, __hip_bfloat16* __restrict__ agg,
                 int N)
{
    int wid = (blockIdx.x * 256 + threadIdx.x) >> 6;   // node index
    if (wid >= N) return;
    int lane = threadIdx.x & 63;
    int h = lane >> 4, u = lane & 15;
    int i = wid;
    int beg = rowptr[i], deg = rowptr[i + 1] - beg;
    const short* base = (const short*)qkv;
    const float scale = 0.17677669529663687f; // 1/sqrt(32)

    bf16frag qf[4];
    const short* qr = base + (size_t)i * QKVC + h * 32;
#pragma unroll
    for (int c = 0; c < 4; ++c) qf[c] = *(const bf16frag*)(qr + c * 8);

    float m_run = -3.4e38f, d_run = 0.f;
    float accx = 0.f, accy = 0.f;

    int j = (u < deg) ? srcperm[beg + u] : i;
    bf16frag kf[4];
    {
        const short* kr = base + (size_t)j * QKVC + 128 + h * 32;
#pragma unroll
        for (int c = 0; c < 4; ++c) kf[c] = *(const bf16frag*)(kr + c * 8);
    }

    for (int c0 = 0; c0 < deg; c0 += 16) {
        int cn = min(16, deg - c0);
        bool valid = (u < cn);

        int nxt = c0 + 16 + u;
        int jn = (nxt < deg) ? srcperm[beg + nxt] : i;

        float dot = 0.f;
#pragma unroll
        for (int c = 0; c < 4; ++c)
#pragma unroll
            for (int e = 0; e < 8; ++e)
                dot += b2f(qf[c][e]) * b2f(kf[c][e]);
        float alpha = valid ? dot * scale : -3.4e38f;

        float cm = alpha;
#pragma unroll
        for (int off = 8; off; off >>= 1) cm = fmaxf(cm, __shfl_xor(cm, off));
        float m_new = fmaxf(m_run, cm);
        float rescale = __expf(m_run - m_new);
        float w = valid ? __expf(alpha - m_new) : 0.f;
        float dsum = w;
#pragma unroll
        for (int off = 8; off; off >>= 1) dsum += __shfl_xor(dsum, off);
        d_run = d_run * rescale + dsum;
        m_run = m_new;
        accx *= rescale;
        accy *= rescale;

        bf16frag kfn[4];
        {
            const short* krn = base + (size_t)jn * QKVC + 128 + h * 32;
#pragma unroll
            for (int c = 0; c < 4; ++c) kfn[c] = *(const bf16frag*)(krn + c * 8);
        }

        float wes[16];
        unsigned vws[16];
#pragma unroll
        for (int e = 0; e < 16; ++e) {
            wes[e] = __shfl(w, h * 16 + e);
            int je = __shfl(j, h * 16 + e);        // invalid slots -> row i
            vws[e] = *(const unsigned*)(base + (size_t)je * QKVC + 256 + h * 32 + u * 2);
        }
#pragma unroll
        for (int e = 0; e < 16; ++e) {
            accx += wes[e] * b2f((short)(vws[e] & 0xffff));
            accy += wes[e] * b2f((short)(vws[e] >> 16));
        }
        j = jn;
#pragma unroll
        for (int c = 0; c < 4; ++c) kf[c] = kfn[c];
    }

    float inv = 1.f / (d_run + 1e-16f);
    __hip_bfloat16* outp = agg + (size_t)i * INNERC + h * 32 + u * 2;
    outp[0] = __float2bfloat16(accx * inv);
    outp[1] = __float2bfloat16(accy * inv);
}

// ---------------- Launch ----------------
extern "C" void kernel_launch(void* const* d_in, const int* in_sizes, int n_in,
                              void* d_out, int out_size, void* d_ws, size_t ws_size,
                              hipStream_t stream)
{
    const float* x    = (const float*)d_in[0];
    const int*   ei   = (const int*)  d_in[1];
    const float* ln1g = (const float*)d_in[2];
    const float* ln1b = (const float*)d_in[3];
    const float* wq   = (const float*)d_in[4];
    const float* bq   = (const float*)d_in[5];
    const float* wk   = (const float*)d_in[6];
    const float* bk   = (const float*)d_in[7];
    const float* wv   = (const float*)d_in[8];
    const float* bv   = (const float*)d_in[9];
    const float* wo   = (const float*)d_in[10];
    const float* bo   = (const float*)d_in[11];
    const float* ln2g = (const float*)d_in[12];
    const float* ln2b = (const float*)d_in[13];
    const float* w1   = (const float*)d_in[14];
    const float* b1   = (const float*)d_in[15];
    const float* w2   = (const float*)d_in[16];
    const float* b2   = (const float*)d_in[17];

    const int N = in_sizes[0] / DIMC;   // 20000
    const int E = in_sizes[1] / 2;      // 320000
    const int* srcIdx = ei;
    const int* dstIdx = ei + E;

    char* p = (char*)d_ws;
    auto alloc = [&](size_t bytes) {
        char* r = p;
        p += (bytes + 255) & ~(size_t)255;
        return r;
    };
    float*          xbuf   = (float*)alloc((size_t)N * DIMC * 4);
    __hip_bfloat16* h      = (__hip_bfloat16*)alloc((size_t)N * DIMC * 2);
    __hip_bfloat16* qkv    = (__hip_bfloat16*)alloc((size_t)N * QKVC * 2);
    __hip_bfloat16* agg    = (__hip_bfloat16*)alloc((size_t)N * INNERC * 2);
    __hip_bfloat16* u      = (__hip_bfloat16*)alloc((size_t)N * 1024 * 2);
    int*            rowptr = (int*)alloc((size_t)(N + 1) * 4);
    int*            cnt    = (int*)alloc((size_t)N * 4);
    int*            bsum   = (int*)alloc((size_t)64 * 4);
    int*            srcperm= (int*)alloc((size_t)E * 4);
    __hip_bfloat16* wqkvB  = (__hip_bfloat16*)alloc((size_t)4 * QKVC * DIMC * 2);
    float*          bqkvF  = (float*)alloc((size_t)4 * QKVC * 4);
    __hip_bfloat16* woB    = (__hip_bfloat16*)alloc((size_t)4 * DIMC * INNERC * 2);
    __hip_bfloat16* w1B    = (__hip_bfloat16*)alloc((size_t)4 * 1024 * DIMC * 2);
    __hip_bfloat16* w2B    = (__hip_bfloat16*)alloc((size_t)4 * DIMC * 1024 * 2);

    // Weight conversion (per-call, deterministic)
    packqkv_kernel<<<4 * QKVC, 256, 0, stream>>>(wq, wk, wv, bq, bk, bv, wqkvB, bqkvF);
    {
        int n = 4 * DIMC * INNERC;
        f2b_kernel<<<(n / 4 + 255) / 256, 256, 0, stream>>>(wo, woB, n);
        n = 4 * 1024 * DIMC;
        f2b_kernel<<<(n / 4 + 255) / 256, 256, 0, stream>>>(w1, w1B, n);
        f2b_kernel<<<(n / 4 + 255) / 256, 256, 0, stream>>>(w2, w2B, n);
    }

    // CSR build (hierarchical scan)
    int nb = (N + 1023) / 1024;     // 20
    hipMemsetAsync(cnt, 0, (size_t)N * 4, stream);
    count_kernel<<<(E + 255) / 256, 256, 0, stream>>>(dstIdx, cnt, E);
    scanA_kernel<<<nb, 1024, 0, stream>>>(cnt, rowptr, bsum, N);
    scanB_kernel<<<1, 64, 0, stream>>>(bsum, nb);
    scanC_kernel<<<nb, 1024, 0, stream>>>(rowptr, bsum, N);
    hipMemsetAsync(cnt, 0, (size_t)N * 4, stream);
    scatter_kernel<<<(E + 255) / 256, 256, 0, stream>>>(srcIdx, dstIdx, rowptr, cnt, srcperm, E);

    int mt = (N + 127) / 128;        // 157
    int mt64 = (N + 63) / 64;        // 313
    int lnBlocks = (N + 3) / 4;      // 5000
    int attnBlocks = (N * 64 + 255) / 256;
    for (int l = 0; l < 4; ++l) {
        const float* xin = (l == 0) ? x : xbuf;
        ln_kernel<<<lnBlocks, 256, 0, stream>>>(xin, ln1g + l * DIMC, ln1b + l * DIMC, h, N);
        // QKV: OUT=384, BM=64 -> 939 blocks
        mfma_gemm<0, 64><<<mt64 * 3, 512, 0, stream>>>(
            h, wqkvB + (size_t)l * QKVC * DIMC, bqkvF + l * QKVC, nullptr,
            qkv, N, DIMC, QKVC, mt64, 3);
        attn_kernel<<<attnBlocks, 256, 0, stream>>>(qkv, rowptr, srcperm, agg, N);
        // out-proj: OUT=256, K=128, BM=64 -> 626 blocks
        mfma_gemm<2, 64><<<mt64 * 2, 512, 0, stream>>>(
            agg, woB + (size_t)l * DIMC * INNERC, bo + l * DIMC, xin,
            xbuf, N, INNERC, DIMC, mt64, 2);
        ln_kernel<<<lnBlocks, 256, 0, stream>>>(xbuf, ln2g + l * DIMC, ln2b + l * DIMC, h, N);
        // FF1: OUT=1024, BM=128 -> 1256 blocks
        mfma_gemm<1, 128><<<mt * 8, 512, 0, stream>>>(
            h, w1B + (size_t)l * 1024 * DIMC, b1 + l * 1024, nullptr,
            u, N, DIMC, 1024, mt, 8);
        float* xout = (l == 3) ? (float*)d_out : xbuf;
        // FF2: OUT=256, K=1024, BM=64 -> 626 blocks, 16 K-steps
        mfma_gemm<2, 64><<<mt64 * 2, 512, 0, stream>>>(
            u, w2B + (size_t)l * DIMC * 1024, b2 + l * DIMC, xbuf,
            xout, N, 1024, DIMC, mt64, 2);
    }
}

// Round 19
// 501.086 us; speedup vs baseline: 1.1370x; 1.0164x over previous
//
#include <hip/hip_runtime.h>
#include <hip/hip_bf16.h>
#include <math.h>

#define DIMC 256
#define INNERC 128
#define HEADSC 4
#define DHC 32
#define QKVC 384

typedef __attribute__((ext_vector_type(8))) short bf16frag;   // 8 bf16 = 4 VGPRs
typedef __attribute__((ext_vector_type(4))) float f32x4;

__device__ __forceinline__ float gelu_exact(float x) {
    return 0.5f * x * (1.0f + erff(x * 0.70710678118654752f));
}

__device__ __forceinline__ float b2f(short s) {
    return __uint_as_float(((unsigned)(unsigned short)s) << 16);
}

__device__ __forceinline__ void gload_lds16(const void* g, void* l) {
    __builtin_amdgcn_global_load_lds(
        (const __attribute__((address_space(1))) void*)g,
        (__attribute__((address_space(3))) void*)l, 16, 0, 0);
}

// ---------------- LayerNorm: one WAVE per row, no barriers ----------------
__global__ __launch_bounds__(256)
void ln_kernel(const float* __restrict__ x, const float* __restrict__ g,
               const float* __restrict__ b, __hip_bfloat16* __restrict__ out,
               int N)
{
    int row = blockIdx.x * 4 + (threadIdx.x >> 6);
    if (row >= N) return;
    int lane = threadIdx.x & 63;
    float4 v = *(const float4*)(x + (size_t)row * DIMC + lane * 4);
    float s = v.x + v.y + v.z + v.w;
    float s2 = v.x * v.x + v.y * v.y + v.z * v.z + v.w * v.w;
#pragma unroll
    for (int off = 32; off; off >>= 1) {
        s += __shfl_xor(s, off);
        s2 += __shfl_xor(s2, off);
    }
    float mean = s * (1.f / DIMC);
    float var = s2 * (1.f / DIMC) - mean * mean;
    float rs = rsqrtf(var + 1e-5f);
    float4 gv = *(const float4*)(g + lane * 4);
    float4 bv = *(const float4*)(b + lane * 4);
    __hip_bfloat16 o[4];
    o[0] = __float2bfloat16((v.x - mean) * rs * gv.x + bv.x);
    o[1] = __float2bfloat16((v.y - mean) * rs * gv.y + bv.y);
    o[2] = __float2bfloat16((v.z - mean) * rs * gv.z + bv.z);
    o[3] = __float2bfloat16((v.w - mean) * rs * gv.w + bv.w);
    *(short4*)(out + (size_t)row * DIMC + lane * 4) = *(short4*)o;
}

// ---------------- unified weight prep: one kernel, all conversions ----------
// Row space (per layer l of 4):
//   rows [0,384)        : wqkv row  (from wq/wk/wv, K=256) + bqkv
//   rows [384,512)      : wo row    (K=... wo is [256][128] row-major l-major)
//   ... simpler: linear task space over all bf16 destination rows.
// Layout: task = blockIdx.x; 256 threads convert one 256-float row slice.
__global__ __launch_bounds__(256)
void prep_kernel(const float* __restrict__ wq, const float* __restrict__ wk,
                 const float* __restrict__ wv, const float* __restrict__ bq,
                 const float* __restrict__ bk, const float* __restrict__ bv,
                 const float* __restrict__ wo, const float* __restrict__ w1,
                 const float* __restrict__ w2,
                 __hip_bfloat16* __restrict__ wqkvB, float* __restrict__ bqkvF,
                 __hip_bfloat16* __restrict__ woB,
                 __hip_bfloat16* __restrict__ w1B,
                 __hip_bfloat16* __restrict__ w2B)
{
    int task = blockIdx.x;
    int t = threadIdx.x;
    // region sizes in 256-element rows:
    // wqkv: 4*384 = 1536 rows of 256
    // wo:   4*256*128 = 131072 el = 512 rows of 256
    // w1:   4*1024*256 = 1048576 el = 4096 rows
    // w2:   4*256*1024 = 1048576 el = 4096 rows
    if (task < 1536) {
        int l = task / QKVC, c = task % QKVC;
        int which = c >> 7, cc = c & 127;
        const float* srcw = which == 0 ? wq : which == 1 ? wk : wv;
        const float* srcb = which == 0 ? bq : which == 1 ? bk : bv;
        srcw += ((size_t)l * INNERC + cc) * DIMC;
        wqkvB[(size_t)task * DIMC + t] = __float2bfloat16(srcw[t]);
        if (t == 0) bqkvF[task] = srcb[l * INNERC + cc];
        return;
    }
    task -= 1536;
    const float* src;
    __hip_bfloat16* dst;
    if (task < 512)       { src = wo; dst = woB; }
    else if (task < 4608) { task -= 512;  src = w1; dst = w1B; }
    else                  { task -= 4608; src = w2; dst = w2B; }
    size_t idx = (size_t)task * 256 + t;
    dst[idx] = __float2bfloat16(src[idx]);
}

// ---------------- MFMA GEMM v8: templated BM (128 or 64), BN=128 ------------
// dbuf + counted vmcnt, hoisted pointers, setprio, LDS-staged epilogue.
// EPI: 0 = bias -> bf16; 1 = bias+gelu -> bf16; 2 = bias+res -> fp32.
template<int EPI, int BM>
__global__ __launch_bounds__(512)
void mfma_gemm(const __hip_bfloat16* __restrict__ A,
               const __hip_bfloat16* __restrict__ W,
               const float* __restrict__ bias, const float* __restrict__ res,
               void* __restrict__ Cout, int M, int K, int OUT,
               int mtiles, int ntiles)
{
    constexpr int ASZ = BM * 128;           // one A buf
    constexpr int WSZ = 128 * 128;          // one W buf (16KB)
    constexpr int EPAD = 132;               // fp32 tile row stride (floats)
    constexpr int KSZ = 2 * ASZ + 2 * WSZ;
    constexpr int ESZ = BM * EPAD * 4;
    constexpr int LDSZ = (KSZ > ESZ) ? KSZ : ESZ;
    constexpr int MFR = BM / 32;            // acc row-frags per wave (4 or 2)
    constexpr int ALD = (BM * 8) / 512;     // A loads/thread (2 or 1)
    __shared__ char lds[LDSZ];

    int nwg = mtiles * ntiles;
    int orig = blockIdx.x;
    int q = nwg >> 3, r = nwg & 7;
    int xcd = orig & 7, loc = orig >> 3;
    int wgid = (xcd < r ? xcd * (q + 1) : r * (q + 1) + (xcd - r) * q) + loc;
    int bm = (wgid / ntiles) * BM;
    int bn = (wgid % ntiles) * 128;

    int tid = threadIdx.x;
    int lane = tid & 63;
    int w = tid >> 6;                        // 0..7
    int wr = w >> 2, wc = w & 3;             // 2 x 4 wave grid
    int l15 = lane & 15, l4 = lane >> 4;

    // ---- hoisted staging addresses (computed once) ----
    const char* aSrc[ALD];
    const char* wSrc[2];
    int aOff[ALD], wOff[2];
#pragma unroll
    for (int it = 0; it < ALD; ++it) {
        int chunk = it * 512 + tid;
        int rr = chunk >> 3;
        int sc = (chunk & 7) ^ (rr & 7);
        int grow = min(bm + rr, M - 1);      // clamp: ALWAYS issue
        aSrc[it] = (const char*)A + ((size_t)grow * K) * 2 + sc * 16;
        aOff[it] = chunk * 16;
    }
#pragma unroll
    for (int it = 0; it < 2; ++it) {
        int chunk = it * 512 + tid;
        int rr = chunk >> 3;
        int sc = (chunk & 7) ^ (rr & 7);
        wSrc[it] = (const char*)W + ((size_t)(bn + rr) * K) * 2 + sc * 16;
        wOff[it] = chunk * 16;
    }

    f32x4 acc[MFR][2] = {};

    auto stage = [&](int b) {
        char* Asb = lds + b * ASZ;
        char* Wsb = lds + 2 * ASZ + b * WSZ;
#pragma unroll
        for (int it = 0; it < ALD; ++it) {
            gload_lds16(aSrc[it], Asb + aOff[it]);
            aSrc[it] += 128;                 // 64 bf16 = one K-step
        }
#pragma unroll
        for (int it = 0; it < 2; ++it) {
            gload_lds16(wSrc[it], Wsb + wOff[it]);
            wSrc[it] += 128;
        }
    };

    int nk = K >> 6;
    stage(0);
    for (int t = 0; t < nk; ++t) {
        int cur = t & 1;
        if (t + 1 < nk) {
            stage(cur ^ 1);                              // prefetch next tile
            if constexpr (BM == 128)
                asm volatile("s_waitcnt vmcnt(4)" ::: "memory");  // tile t only
            else
                asm volatile("s_waitcnt vmcnt(3)" ::: "memory");
        } else {
            asm volatile("s_waitcnt vmcnt(0)" ::: "memory");
        }
        __builtin_amdgcn_s_barrier();                    // tile t visible
        char* As = lds + cur * ASZ;
        char* Ws = lds + 2 * ASZ + cur * WSZ;
#pragma unroll
        for (int s = 0; s < 2; ++s) {
            bf16frag af[MFR], bfr[2];
            int kb = s * 64 + (l4 << 4);
#pragma unroll
            for (int m = 0; m < MFR; ++m) {
                int ar = wr * (BM / 2) + m * 16 + l15;
                af[m] = *(const bf16frag*)(As + ar * 128 + (kb ^ ((ar & 7) << 4)));
            }
#pragma unroll
            for (int n = 0; n < 2; ++n) {
                int br = wc * 32 + n * 16 + l15;
                bfr[n] = *(const bf16frag*)(Ws + br * 128 + (kb ^ ((br & 7) << 4)));
            }
            __builtin_amdgcn_s_setprio(1);
#pragma unroll
            for (int m = 0; m < MFR; ++m)
#pragma unroll
                for (int n = 0; n < 2; ++n)
                    acc[m][n] = __builtin_amdgcn_mfma_f32_16x16x32_bf16(
                        af[m], bfr[n], acc[m][n], 0, 0, 0);
            __builtin_amdgcn_s_setprio(0);
        }
        __builtin_amdgcn_s_barrier();                    // WAR on buf
    }

    // ---- epilogue: stage fp32 tile to LDS, then coalesced writes ----
    float* tile = (float*)lds;               // [BM][EPAD]
    __syncthreads();                          // all LDS K-loop reads done
#pragma unroll
    for (int m = 0; m < MFR; ++m)
#pragma unroll
        for (int rr = 0; rr < 4; ++rr) {
            int lrow = wr * (BM / 2) + m * 16 + (l4 << 2) + rr;
#pragma unroll
            for (int n = 0; n < 2; ++n) {
                int lcol = wc * 32 + n * 16 + l15;
                float val = acc[m][n][rr] + bias[bn + lcol];
                if (EPI == 1) val = gelu_exact(val);
                tile[lrow * EPAD + lcol] = val;
            }
        }
    __syncthreads();

    if (EPI == 2) {
        int rp = tid >> 5, c4 = (tid & 31) * 4;
        float* outF = (float*)Cout;
#pragma unroll
        for (int pass = 0; pass < BM / 16; ++pass) {
            int lrow = pass * 16 + rp;
            int grow = bm + lrow;
            if (grow < M) {
                float4 v = *(float4*)&tile[lrow * EPAD + c4];
                const float4 rv = *(const float4*)&res[(size_t)grow * OUT + bn + c4];
                v.x += rv.x; v.y += rv.y; v.z += rv.z; v.w += rv.w;
                *(float4*)&outF[(size_t)grow * OUT + bn + c4] = v;
            }
        }
    } else {
        int rp = tid >> 5, c4 = (tid & 31) * 4;
        __hip_bfloat16* outB = (__hip_bfloat16*)Cout;
#pragma unroll
        for (int pass = 0; pass < BM / 16; ++pass) {
            int lrow = pass * 16 + rp;
            int grow = bm + lrow;
            if (grow < M) {
                float4 v = *(float4*)&tile[lrow * EPAD + c4];
                __hip_bfloat16 o[4];
                o[0] = __float2bfloat16(v.x);
                o[1] = __float2bfloat16(v.y);
                o[2] = __float2bfloat16(v.z);
                o[3] = __float2bfloat16(v.w);
                *(short4*)&outB[(size_t)grow * OUT + bn + c4] = *(short4*)o;
            }
        }
    }
}

// ---------------- CSR build: count + hierarchical scan + scatter ------------
__global__ void count_kernel(const int* __restrict__ dst, int* __restrict__ count, int E)
{
    int e = blockIdx.x * blockDim.x + threadIdx.x;
    if (e < E) atomicAdd(&count[dst[e]], 1);
}

__global__ __launch_bounds__(1024)
void scanA_kernel(const int* __restrict__ count, int* __restrict__ rowptr,
                  int* __restrict__ bsum, int N)
{
    __shared__ int sdata[1024];
    int b = blockIdx.x, t = threadIdx.x;
    int idx = b * 1024 + t;
    int v = (idx < N) ? count[idx] : 0;
    sdata[t] = v;
    __syncthreads();
    for (int off = 1; off < 1024; off <<= 1) {
        int add = (t >= off) ? sdata[t - off] : 0;
        __syncthreads();
        sdata[t] += add;
        __syncthreads();
    }
    if (idx < N) rowptr[idx + 1] = sdata[t];
    if (t == 1023) bsum[b] = sdata[1023];
}

__global__ void scanB_kernel(int* __restrict__ bsum, int nb)
{
    int t = threadIdx.x;
    int v = (t < nb) ? bsum[t] : 0;
#pragma unroll
    for (int off = 1; off < 64; off <<= 1) {
        int u = __shfl_up(v, off);
        if (t >= off) v += u;
    }
    if (t < nb) bsum[t] = v;
}

__global__ __launch_bounds__(1024)
void scanC_kernel(int* __restrict__ rowptr, const int* __restrict__ bsum, int N)
{
    int b = blockIdx.x, t = threadIdx.x;
    int idx = b * 1024 + t;
    if (idx == 0) rowptr[0] = 0;
    if (idx < N && b > 0) rowptr[idx + 1] += bsum[b - 1];
}

__global__ void scatter_kernel(const int* __restrict__ src, const int* __restrict__ dst,
                               const int* __restrict__ rowptr, int* __restrict__ cursor,
                               int* __restrict__ srcperm, int E)
{
    int e = blockIdx.x * blockDim.x + threadIdx.x;
    if (e < E) {
        int d = dst[e];
        int pos = rowptr[d] + atomicAdd(&cursor[d], 1);
        srcperm[pos] = src[e];
    }
}

// ---------------- Attention: wave/node, cross-chunk K prefetch --------------
__global__ __launch_bounds__(256)
void attn_kernel(const __hip_bfloat16* __restrict__ qkv, const int* __restrict__ rowptr,
                 const int* __restrict__ srcperm, __hip_bfloat16* __restrict__ agg,
                 int N)
{
    int wid = (blockIdx.x * 256 + threadIdx.x) >> 6;   // node index
    if (wid >= N) return;
    int lane = threadIdx.x & 63;
    int h = lane >> 4, u = lane & 15;
    int i = wid;
    int beg = rowptr[i], deg = rowptr[i + 1] - beg;
    const short* base = (const short*)qkv;
    const float scale = 0.17677669529663687f; // 1/sqrt(32)

    bf16frag qf[4];
    const short* qr = base + (size_t)i * QKVC + h * 32;
#pragma unroll
    for (int c = 0; c < 4; ++c) qf[c] = *(const bf16frag*)(qr + c * 8);

    float m_run = -3.4e38f, d_run = 0.f;
    float accx = 0.f, accy = 0.f;

    int j = (u < deg) ? srcperm[beg + u] : i;
    bf16frag kf[4];
    {
        const short* kr = base + (size_t)j * QKVC + 128 + h * 32;
#pragma unroll
        for (int c = 0; c < 4; ++c) kf[c] = *(const bf16frag*)(kr + c * 8);
    }

    for (int c0 = 0; c0 < deg; c0 += 16) {
        int cn = min(16, deg - c0);
        bool valid = (u < cn);

        int nxt = c0 + 16 + u;
        int jn = (nxt < deg) ? srcperm[beg + nxt] : i;

        float dot = 0.f;
#pragma unroll
        for (int c = 0; c < 4; ++c)
#pragma unroll
            for (int e = 0; e < 8; ++e)
                dot += b2f(qf[c][e]) * b2f(kf[c][e]);
        float alpha = valid ? dot * scale : -3.4e38f;

        float cm = alpha;
#pragma unroll
        for (int off = 8; off; off >>= 1) cm = fmaxf(cm, __shfl_xor(cm, off));
        float m_new = fmaxf(m_run, cm);
        float rescale = __expf(m_run - m_new);
        float w = valid ? __expf(alpha - m_new) : 0.f;
        float dsum = w;
#pragma unroll
        for (int off = 8; off; off >>= 1) dsum += __shfl_xor(dsum, off);
        d_run = d_run * rescale + dsum;
        m_run = m_new;
        accx *= rescale;
        accy *= rescale;

        bf16frag kfn[4];
        {
            const short* krn = base + (size_t)jn * QKVC + 128 + h * 32;
#pragma unroll
            for (int c = 0; c < 4; ++c) kfn[c] = *(const bf16frag*)(krn + c * 8);
        }

        float wes[16];
        unsigned vws[16];
#pragma unroll
        for (int e = 0; e < 16; ++e) {
            wes[e] = __shfl(w, h * 16 + e);
            int je = __shfl(j, h * 16 + e);        // invalid slots -> row i
            vws[e] = *(const unsigned*)(base + (size_t)je * QKVC + 256 + h * 32 + u * 2);
        }
#pragma unroll
        for (int e = 0; e < 16; ++e) {
            accx += wes[e] * b2f((short)(vws[e] & 0xffff));
            accy += wes[e] * b2f((short)(vws[e] >> 16));
        }
        j = jn;
#pragma unroll
        for (int c = 0; c < 4; ++c) kf[c] = kfn[c];
    }

    float inv = 1.f / (d_run + 1e-16f);
    __hip_bfloat16* outp = agg + (size_t)i * INNERC + h * 32 + u * 2;
    outp[0] = __float2bfloat16(accx * inv);
    outp[1] = __float2bfloat16(accy * inv);
}

// ---------------- Launch ----------------
extern "C" void kernel_launch(void* const* d_in, const int* in_sizes, int n_in,
                              void* d_out, int out_size, void* d_ws, size_t ws_size,
                              hipStream_t stream)
{
    const float* x    = (const float*)d_in[0];
    const int*   ei   = (const int*)  d_in[1];
    const float* ln1g = (const float*)d_in[2];
    const float* ln1b = (const float*)d_in[3];
    const float* wq   = (const float*)d_in[4];
    const float* bq   = (const float*)d_in[5];
    const float* wk   = (const float*)d_in[6];
    const float* bk   = (const float*)d_in[7];
    const float* wv   = (const float*)d_in[8];
    const float* bv   = (const float*)d_in[9];
    const float* wo   = (const float*)d_in[10];
    const float* bo   = (const float*)d_in[11];
    const float* ln2g = (const float*)d_in[12];
    const float* ln2b = (const float*)d_in[13];
    const float* w1   = (const float*)d_in[14];
    const float* b1   = (const float*)d_in[15];
    const float* w2   = (const float*)d_in[16];
    const float* b2   = (const float*)d_in[17];

    const int N = in_sizes[0] / DIMC;   // 20000
    const int E = in_sizes[1] / 2;      // 320000
    const int* srcIdx = ei;
    const int* dstIdx = ei + E;

    char* p = (char*)d_ws;
    auto alloc = [&](size_t bytes) {
        char* r = p;
        p += (bytes + 255) & ~(size_t)255;
        return r;
    };
    float*          xbuf   = (float*)alloc((size_t)N * DIMC * 4);
    __hip_bfloat16* h      = (__hip_bfloat16*)alloc((size_t)N * DIMC * 2);
    __hip_bfloat16* qkv    = (__hip_bfloat16*)alloc((size_t)N * QKVC * 2);
    __hip_bfloat16* agg    = (__hip_bfloat16*)alloc((size_t)N * INNERC * 2);
    __hip_bfloat16* u      = (__hip_bfloat16*)alloc((size_t)N * 1024 * 2);
    int*            rowptr = (int*)alloc((size_t)(N + 1) * 4);
    int*            cnt    = (int*)alloc((size_t)N * 4);
    int*            bsum   = (int*)alloc((size_t)64 * 4);
    int*            srcperm= (int*)alloc((size_t)E * 4);
    __hip_bfloat16* wqkvB  = (__hip_bfloat16*)alloc((size_t)4 * QKVC * DIMC * 2);
    float*          bqkvF  = (float*)alloc((size_t)4 * QKVC * 4);
    __hip_bfloat16* woB    = (__hip_bfloat16*)alloc((size_t)4 * DIMC * INNERC * 2);
    __hip_bfloat16* w1B    = (__hip_bfloat16*)alloc((size_t)4 * 1024 * DIMC * 2);
    __hip_bfloat16* w2B    = (__hip_bfloat16*)alloc((size_t)4 * DIMC * 1024 * 2);

    // Unified weight prep: 1536 + 512 + 4096 + 4096 = 10240 tasks, 1 launch
    prep_kernel<<<10240, 256, 0, stream>>>(wq, wk, wv, bq, bk, bv, wo, w1, w2,
                                           wqkvB, bqkvF, woB, w1B, w2B);

    // CSR build (hierarchical scan)
    int nb = (N + 1023) / 1024;     // 20
    hipMemsetAsync(cnt, 0, (size_t)N * 4, stream);
    count_kernel<<<(E + 255) / 256, 256, 0, stream>>>(dstIdx, cnt, E);
    scanA_kernel<<<nb, 1024, 0, stream>>>(cnt, rowptr, bsum, N);
    scanB_kernel<<<1, 64, 0, stream>>>(bsum, nb);
    scanC_kernel<<<nb, 1024, 0, stream>>>(rowptr, bsum, N);
    hipMemsetAsync(cnt, 0, (size_t)N * 4, stream);
    scatter_kernel<<<(E + 255) / 256, 256, 0, stream>>>(srcIdx, dstIdx, rowptr, cnt, srcperm, E);

    int mt = (N + 127) / 128;        // 157
    int mt64 = (N + 63) / 64;        // 313
    int lnBlocks = (N + 3) / 4;      // 5000
    int attnBlocks = (N * 64 + 255) / 256;
    for (int l = 0; l < 4; ++l) {
        const float* xin = (l == 0) ? x : xbuf;
        ln_kernel<<<lnBlocks, 256, 0, stream>>>(xin, ln1g + l * DIMC, ln1b + l * DIMC, h, N);
        // QKV: OUT=384, BM=128 -> 471 blocks
        mfma_gemm<0, 128><<<mt * 3, 512, 0, stream>>>(
            h, wqkvB + (size_t)l * QKVC * DIMC, bqkvF + l * QKVC, nullptr,
            qkv, N, DIMC, QKVC, mt, 3);
        attn_kernel<<<attnBlocks, 256, 0, stream>>>(qkv, rowptr, srcperm, agg, N);
        // out-proj: OUT=256, K=128, BM=64 -> 626 blocks
        mfma_gemm<2, 64><<<mt64 * 2, 512, 0, stream>>>(
            agg, woB + (size_t)l * DIMC * INNERC, bo + l * DIMC, xin,
            xbuf, N, INNERC, DIMC, mt64, 2);
        ln_kernel<<<lnBlocks, 256, 0, stream>>>(xbuf, ln2g + l * DIMC, ln2b + l * DIMC, h, N);
        // FF1: OUT=1024, BM=128 -> 1256 blocks
        mfma_gemm<1, 128><<<mt * 8, 512, 0, stream>>>(
            h, w1B + (size_t)l * 1024 * DIMC, b1 + l * 1024, nullptr,
            u, N, DIMC, 1024, mt, 8);
        float* xout = (l == 3) ? (float*)d_out : xbuf;
        // FF2: OUT=256, K=1024, BM=64 -> 626 blocks, 16 K-steps
        mfma_gemm<2, 64><<<mt64 * 2, 512, 0, stream>>>(
            u, w2B + (size_t)l * DIMC * 1024, b2 + l * DIMC, xbuf,
            xout, N, 1024, DIMC, mt64, 2);
    }
}

// Round 20
// 494.017 us; speedup vs baseline: 1.1532x; 1.0143x over previous
//
#include <hip/hip_runtime.h>
#include <hip/hip_bf16.h>
#include <math.h>

#define DIMC 256
#define INNERC 128
#define HEADSC 4
#define DHC 32
#define QKVC 384

typedef __attribute__((ext_vector_type(8))) short bf16frag;   // 8 bf16 = 4 VGPRs
typedef __attribute__((ext_vector_type(4))) float f32x4;

__device__ __forceinline__ float gelu_exact(float x) {
    return 0.5f * x * (1.0f + erff(x * 0.70710678118654752f));
}

__device__ __forceinline__ float b2f(short s) {
    return __uint_as_float(((unsigned)(unsigned short)s) << 16);
}

__device__ __forceinline__ void gload_lds16(const void* g, void* l) {
    __builtin_amdgcn_global_load_lds(
        (const __attribute__((address_space(1))) void*)g,
        (__attribute__((address_space(3))) void*)l, 16, 0, 0);
}

// ---------------- LayerNorm: one WAVE per row, no barriers ----------------
__global__ __launch_bounds__(256)
void ln_kernel(const float* __restrict__ x, const float* __restrict__ g,
               const float* __restrict__ b, __hip_bfloat16* __restrict__ out,
               int N)
{
    int row = blockIdx.x * 4 + (threadIdx.x >> 6);
    if (row >= N) return;
    int lane = threadIdx.x & 63;
    float4 v = *(const float4*)(x + (size_t)row * DIMC + lane * 4);
    float s = v.x + v.y + v.z + v.w;
    float s2 = v.x * v.x + v.y * v.y + v.z * v.z + v.w * v.w;
#pragma unroll
    for (int off = 32; off; off >>= 1) {
        s += __shfl_xor(s, off);
        s2 += __shfl_xor(s2, off);
    }
    float mean = s * (1.f / DIMC);
    float var = s2 * (1.f / DIMC) - mean * mean;
    float rs = rsqrtf(var + 1e-5f);
    float4 gv = *(const float4*)(g + lane * 4);
    float4 bv = *(const float4*)(b + lane * 4);
    __hip_bfloat16 o[4];
    o[0] = __float2bfloat16((v.x - mean) * rs * gv.x + bv.x);
    o[1] = __float2bfloat16((v.y - mean) * rs * gv.y + bv.y);
    o[2] = __float2bfloat16((v.z - mean) * rs * gv.z + bv.z);
    o[3] = __float2bfloat16((v.w - mean) * rs * gv.w + bv.w);
    *(short4*)(out + (size_t)row * DIMC + lane * 4) = *(short4*)o;
}

// ---------------- unified weight prep: one kernel, all conversions ----------
__global__ __launch_bounds__(256)
void prep_kernel(const float* __restrict__ wq, const float* __restrict__ wk,
                 const float* __restrict__ wv, const float* __restrict__ bq,
                 const float* __restrict__ bk, const float* __restrict__ bv,
                 const float* __restrict__ wo, const float* __restrict__ w1,
                 const float* __restrict__ w2,
                 __hip_bfloat16* __restrict__ wqkvB, float* __restrict__ bqkvF,
                 __hip_bfloat16* __restrict__ woB,
                 __hip_bfloat16* __restrict__ w1B,
                 __hip_bfloat16* __restrict__ w2B)
{
    int task = blockIdx.x;
    int t = threadIdx.x;
    if (task < 1536) {
        int l = task / QKVC, c = task % QKVC;
        int which = c >> 7, cc = c & 127;
        const float* srcw = which == 0 ? wq : which == 1 ? wk : wv;
        const float* srcb = which == 0 ? bq : which == 1 ? bk : bv;
        srcw += ((size_t)l * INNERC + cc) * DIMC;
        wqkvB[(size_t)task * DIMC + t] = __float2bfloat16(srcw[t]);
        if (t == 0) bqkvF[task] = srcb[l * INNERC + cc];
        return;
    }
    task -= 1536;
    const float* src;
    __hip_bfloat16* dst;
    if (task < 512)       { src = wo; dst = woB; }
    else if (task < 4608) { task -= 512;  src = w1; dst = w1B; }
    else                  { task -= 4608; src = w2; dst = w2B; }
    size_t idx = (size_t)task * 256 + t;
    dst[idx] = __float2bfloat16(src[idx]);
}

// ---------------- MFMA GEMM v8: templated BM (128 or 64), BN=128 ------------
// dbuf + counted vmcnt, hoisted pointers, setprio, LDS-staged epilogue.
// EPI: 0 = bias -> bf16; 1 = bias+gelu -> bf16; 2 = bias+res -> fp32.
template<int EPI, int BM>
__global__ __launch_bounds__(512)
void mfma_gemm(const __hip_bfloat16* __restrict__ A,
               const __hip_bfloat16* __restrict__ W,
               const float* __restrict__ bias, const float* __restrict__ res,
               void* __restrict__ Cout, int M, int K, int OUT,
               int mtiles, int ntiles)
{
    constexpr int ASZ = BM * 128;           // one A buf
    constexpr int WSZ = 128 * 128;          // one W buf (16KB)
    constexpr int EPAD = 132;               // fp32 tile row stride (floats)
    constexpr int KSZ = 2 * ASZ + 2 * WSZ;
    constexpr int ESZ = BM * EPAD * 4;
    constexpr int LDSZ = (KSZ > ESZ) ? KSZ : ESZ;
    constexpr int MFR = BM / 32;            // acc row-frags per wave (4 or 2)
    constexpr int ALD = (BM * 8) / 512;     // A loads/thread (2 or 1)
    __shared__ char lds[LDSZ];

    int nwg = mtiles * ntiles;
    int orig = blockIdx.x;
    int q = nwg >> 3, r = nwg & 7;
    int xcd = orig & 7, loc = orig >> 3;
    int wgid = (xcd < r ? xcd * (q + 1) : r * (q + 1) + (xcd - r) * q) + loc;
    int bm = (wgid / ntiles) * BM;
    int bn = (wgid % ntiles) * 128;

    int tid = threadIdx.x;
    int lane = tid & 63;
    int w = tid >> 6;                        // 0..7
    int wr = w >> 2, wc = w & 3;             // 2 x 4 wave grid
    int l15 = lane & 15, l4 = lane >> 4;

    // ---- hoisted staging addresses (computed once) ----
    const char* aSrc[ALD];
    const char* wSrc[2];
    int aOff[ALD], wOff[2];
#pragma unroll
    for (int it = 0; it < ALD; ++it) {
        int chunk = it * 512 + tid;
        int rr = chunk >> 3;
        int sc = (chunk & 7) ^ (rr & 7);
        int grow = min(bm + rr, M - 1);      // clamp: ALWAYS issue
        aSrc[it] = (const char*)A + ((size_t)grow * K) * 2 + sc * 16;
        aOff[it] = chunk * 16;
    }
#pragma unroll
    for (int it = 0; it < 2; ++it) {
        int chunk = it * 512 + tid;
        int rr = chunk >> 3;
        int sc = (chunk & 7) ^ (rr & 7);
        wSrc[it] = (const char*)W + ((size_t)(bn + rr) * K) * 2 + sc * 16;
        wOff[it] = chunk * 16;
    }

    f32x4 acc[MFR][2] = {};

    auto stage = [&](int b) {
        char* Asb = lds + b * ASZ;
        char* Wsb = lds + 2 * ASZ + b * WSZ;
#pragma unroll
        for (int it = 0; it < ALD; ++it) {
            gload_lds16(aSrc[it], Asb + aOff[it]);
            aSrc[it] += 128;                 // 64 bf16 = one K-step
        }
#pragma unroll
        for (int it = 0; it < 2; ++it) {
            gload_lds16(wSrc[it], Wsb + wOff[it]);
            wSrc[it] += 128;
        }
    };

    int nk = K >> 6;
    stage(0);
    for (int t = 0; t < nk; ++t) {
        int cur = t & 1;
        if (t + 1 < nk) {
            stage(cur ^ 1);                              // prefetch next tile
            if constexpr (BM == 128)
                asm volatile("s_waitcnt vmcnt(4)" ::: "memory");  // tile t only
            else
                asm volatile("s_waitcnt vmcnt(3)" ::: "memory");
        } else {
            asm volatile("s_waitcnt vmcnt(0)" ::: "memory");
        }
        __builtin_amdgcn_s_barrier();                    // tile t visible
        char* As = lds + cur * ASZ;
        char* Ws = lds + 2 * ASZ + cur * WSZ;
#pragma unroll
        for (int s = 0; s < 2; ++s) {
            bf16frag af[MFR], bfr[2];
            int kb = s * 64 + (l4 << 4);
#pragma unroll
            for (int m = 0; m < MFR; ++m) {
                int ar = wr * (BM / 2) + m * 16 + l15;
                af[m] = *(const bf16frag*)(As + ar * 128 + (kb ^ ((ar & 7) << 4)));
            }
#pragma unroll
            for (int n = 0; n < 2; ++n) {
                int br = wc * 32 + n * 16 + l15;
                bfr[n] = *(const bf16frag*)(Ws + br * 128 + (kb ^ ((br & 7) << 4)));
            }
            __builtin_amdgcn_s_setprio(1);
#pragma unroll
            for (int m = 0; m < MFR; ++m)
#pragma unroll
                for (int n = 0; n < 2; ++n)
                    acc[m][n] = __builtin_amdgcn_mfma_f32_16x16x32_bf16(
                        af[m], bfr[n], acc[m][n], 0, 0, 0);
            __builtin_amdgcn_s_setprio(0);
        }
        __builtin_amdgcn_s_barrier();                    // WAR on buf
    }

    // ---- epilogue: stage fp32 tile to LDS, then coalesced writes ----
    float* tile = (float*)lds;               // [BM][EPAD]
    __syncthreads();                          // all LDS K-loop reads done
#pragma unroll
    for (int m = 0; m < MFR; ++m)
#pragma unroll
        for (int rr = 0; rr < 4; ++rr) {
            int lrow = wr * (BM / 2) + m * 16 + (l4 << 2) + rr;
#pragma unroll
            for (int n = 0; n < 2; ++n) {
                int lcol = wc * 32 + n * 16 + l15;
                float val = acc[m][n][rr] + bias[bn + lcol];
                if (EPI == 1) val = gelu_exact(val);
                tile[lrow * EPAD + lcol] = val;
            }
        }
    __syncthreads();

    if (EPI == 2) {
        int rp = tid >> 5, c4 = (tid & 31) * 4;
        float* outF = (float*)Cout;
#pragma unroll
        for (int pass = 0; pass < BM / 16; ++pass) {
            int lrow = pass * 16 + rp;
            int grow = bm + lrow;
            if (grow < M) {
                float4 v = *(float4*)&tile[lrow * EPAD + c4];
                const float4 rv = *(const float4*)&res[(size_t)grow * OUT + bn + c4];
                v.x += rv.x; v.y += rv.y; v.z += rv.z; v.w += rv.w;
                *(float4*)&outF[(size_t)grow * OUT + bn + c4] = v;
            }
        }
    } else {
        int rp = tid >> 5, c4 = (tid & 31) * 4;
        __hip_bfloat16* outB = (__hip_bfloat16*)Cout;
#pragma unroll
        for (int pass = 0; pass < BM / 16; ++pass) {
            int lrow = pass * 16 + rp;
            int grow = bm + lrow;
            if (grow < M) {
                float4 v = *(float4*)&tile[lrow * EPAD + c4];
                __hip_bfloat16 o[4];
                o[0] = __float2bfloat16(v.x);
                o[1] = __float2bfloat16(v.y);
                o[2] = __float2bfloat16(v.z);
                o[3] = __float2bfloat16(v.w);
                *(short4*)&outB[(size_t)grow * OUT + bn + c4] = *(short4*)o;
            }
        }
    }
}

// ---------------- CSR build: count + hierarchical scan + scatter ------------
__global__ void count_kernel(const int* __restrict__ dst, int* __restrict__ count, int E)
{
    int e = blockIdx.x * blockDim.x + threadIdx.x;
    if (e < E) atomicAdd(&count[dst[e]], 1);
}

__global__ __launch_bounds__(1024)
void scanA_kernel(const int* __restrict__ count, int* __restrict__ rowptr,
                  int* __restrict__ bsum, int N)
{
    __shared__ int sdata[1024];
    int b = blockIdx.x, t = threadIdx.x;
    int idx = b * 1024 + t;
    int v = (idx < N) ? count[idx] : 0;
    sdata[t] = v;
    __syncthreads();
    for (int off = 1; off < 1024; off <<= 1) {
        int add = (t >= off) ? sdata[t - off] : 0;
        __syncthreads();
        sdata[t] += add;
        __syncthreads();
    }
    if (idx < N) rowptr[idx + 1] = sdata[t];
    if (t == 1023) bsum[b] = sdata[1023];
}

__global__ void scanB_kernel(int* __restrict__ bsum, int nb)
{
    int t = threadIdx.x;
    int v = (t < nb) ? bsum[t] : 0;
#pragma unroll
    for (int off = 1; off < 64; off <<= 1) {
        int u = __shfl_up(v, off);
        if (t >= off) v += u;
    }
    if (t < nb) bsum[t] = v;
}

__global__ __launch_bounds__(1024)
void scanC_kernel(int* __restrict__ rowptr, const int* __restrict__ bsum, int N)
{
    int b = blockIdx.x, t = threadIdx.x;
    int idx = b * 1024 + t;
    if (idx == 0) rowptr[0] = 0;
    if (idx < N && b > 0) rowptr[idx + 1] += bsum[b - 1];
}

__global__ void scatter_kernel(const int* __restrict__ src, const int* __restrict__ dst,
                               const int* __restrict__ rowptr, int* __restrict__ cursor,
                               int* __restrict__ srcperm, int E)
{
    int e = blockIdx.x * blockDim.x + threadIdx.x;
    if (e < E) {
        int d = dst[e];
        int pos = rowptr[d] + atomicAdd(&cursor[d], 1);
        srcperm[pos] = src[e];
    }
}

// ---------------- Attention: wave/node, V-loads hoisted above softmax -------
// Lane = h*16+u. Per chunk: srcperm -> issue V gathers (addr = shfl of j,
// known at chunk start) + next-chunk K prefetch -> dot -> softmax -> fma.
// V latency hides under ~300cy of dot+softmax VALU instead of being exposed.
__global__ __launch_bounds__(256)
void attn_kernel(const __hip_bfloat16* __restrict__ qkv, const int* __restrict__ rowptr,
                 const int* __restrict__ srcperm, __hip_bfloat16* __restrict__ agg,
                 int N)
{
    int wid = (blockIdx.x * 256 + threadIdx.x) >> 6;   // node index
    if (wid >= N) return;
    int lane = threadIdx.x & 63;
    int h = lane >> 4, u = lane & 15;
    int i = wid;
    int beg = rowptr[i], deg = rowptr[i + 1] - beg;
    const short* base = (const short*)qkv;
    const float scale = 0.17677669529663687f; // 1/sqrt(32)

    bf16frag qf[4];
    const short* qr = base + (size_t)i * QKVC + h * 32;
#pragma unroll
    for (int c = 0; c < 4; ++c) qf[c] = *(const bf16frag*)(qr + c * 8);

    float m_run = -3.4e38f, d_run = 0.f;
    float accx = 0.f, accy = 0.f;

    int j = (u < deg) ? srcperm[beg + u] : i;
    bf16frag kf[4];
    {
        const short* kr = base + (size_t)j * QKVC + 128 + h * 32;
#pragma unroll
        for (int c = 0; c < 4; ++c) kf[c] = *(const bf16frag*)(kr + c * 8);
    }

    for (int c0 = 0; c0 < deg; c0 += 16) {
        int cn = min(16, deg - c0);
        bool valid = (u < cn);

        // ---- next chunk's edge index ----
        int nxt = c0 + 16 + u;
        int jn = (nxt < deg) ? srcperm[beg + nxt] : i;

        // ---- issue V gathers NOW (addresses need only j) ----
        unsigned vws[16];
#pragma unroll
        for (int e = 0; e < 16; ++e) {
            int je = __shfl(j, h * 16 + e);        // invalid slots -> row i
            vws[e] = *(const unsigned*)(base + (size_t)je * QKVC + 256 + h * 32 + u * 2);
        }

        // ---- issue next chunk's K prefetch ----
        bf16frag kfn[4];
        {
            const short* krn = base + (size_t)jn * QKVC + 128 + h * 32;
#pragma unroll
            for (int c = 0; c < 4; ++c) kfn[c] = *(const bf16frag*)(krn + c * 8);
        }

        // ---- dot (uses prefetched kf) — covers V/K latency ----
        float dot = 0.f;
#pragma unroll
        for (int c = 0; c < 4; ++c)
#pragma unroll
            for (int e = 0; e < 8; ++e)
                dot += b2f(qf[c][e]) * b2f(kf[c][e]);
        float alpha = valid ? dot * scale : -3.4e38f;

        // ---- per-head online softmax (16-lane group reduce) ----
        float cm = alpha;
#pragma unroll
        for (int off = 8; off; off >>= 1) cm = fmaxf(cm, __shfl_xor(cm, off));
        float m_new = fmaxf(m_run, cm);
        float rescale = __expf(m_run - m_new);
        float w = valid ? __expf(alpha - m_new) : 0.f;
        float dsum = w;
#pragma unroll
        for (int off = 8; off; off >>= 1) dsum += __shfl_xor(dsum, off);
        d_run = d_run * rescale + dsum;
        m_run = m_new;
        accx *= rescale;
        accy *= rescale;

        // ---- weights + fma (V data already resident) ----
        float wes[16];
#pragma unroll
        for (int e = 0; e < 16; ++e)
            wes[e] = __shfl(w, h * 16 + e);
#pragma unroll
        for (int e = 0; e < 16; ++e) {
            accx += wes[e] * b2f((short)(vws[e] & 0xffff));
            accy += wes[e] * b2f((short)(vws[e] >> 16));
        }
        j = jn;
#pragma unroll
        for (int c = 0; c < 4; ++c) kf[c] = kfn[c];
    }

    float inv = 1.f / (d_run + 1e-16f);
    __hip_bfloat16* outp = agg + (size_t)i * INNERC + h * 32 + u * 2;
    outp[0] = __float2bfloat16(accx * inv);
    outp[1] = __float2bfloat16(accy * inv);
}

// ---------------- Launch ----------------
extern "C" void kernel_launch(void* const* d_in, const int* in_sizes, int n_in,
                              void* d_out, int out_size, void* d_ws, size_t ws_size,
                              hipStream_t stream)
{
    const float* x    = (const float*)d_in[0];
    const int*   ei   = (const int*)  d_in[1];
    const float* ln1g = (const float*)d_in[2];
    const float* ln1b = (const float*)d_in[3];
    const float* wq   = (const float*)d_in[4];
    const float* bq   = (const float*)d_in[5];
    const float* wk   = (const float*)d_in[6];
    const float* bk   = (const float*)d_in[7];
    const float* wv   = (const float*)d_in[8];
    const float* bv   = (const float*)d_in[9];
    const float* wo   = (const float*)d_in[10];
    const float* bo   = (const float*)d_in[11];
    const float* ln2g = (const float*)d_in[12];
    const float* ln2b = (const float*)d_in[13];
    const float* w1   = (const float*)d_in[14];
    const float* b1   = (const float*)d_in[15];
    const float* w2   = (const float*)d_in[16];
    const float* b2   = (const float*)d_in[17];

    const int N = in_sizes[0] / DIMC;   // 20000
    const int E = in_sizes[1] / 2;      // 320000
    const int* srcIdx = ei;
    const int* dstIdx = ei + E;

    char* p = (char*)d_ws;
    auto alloc = [&](size_t bytes) {
        char* r = p;
        p += (bytes + 255) & ~(size_t)255;
        return r;
    };
    float*          xbuf   = (float*)alloc((size_t)N * DIMC * 4);
    __hip_bfloat16* h      = (__hip_bfloat16*)alloc((size_t)N * DIMC * 2);
    __hip_bfloat16* qkv    = (__hip_bfloat16*)alloc((size_t)N * QKVC * 2);
    __hip_bfloat16* agg    = (__hip_bfloat16*)alloc((size_t)N * INNERC * 2);
    __hip_bfloat16* u      = (__hip_bfloat16*)alloc((size_t)N * 1024 * 2);
    int*            rowptr = (int*)alloc((size_t)(N + 1) * 4);
    int*            cnt    = (int*)alloc((size_t)N * 4);
    int*            bsum   = (int*)alloc((size_t)64 * 4);
    int*            srcperm= (int*)alloc((size_t)E * 4);
    __hip_bfloat16* wqkvB  = (__hip_bfloat16*)alloc((size_t)4 * QKVC * DIMC * 2);
    float*          bqkvF  = (float*)alloc((size_t)4 * QKVC * 4);
    __hip_bfloat16* woB    = (__hip_bfloat16*)alloc((size_t)4 * DIMC * INNERC * 2);
    __hip_bfloat16* w1B    = (__hip_bfloat16*)alloc((size_t)4 * 1024 * DIMC * 2);
    __hip_bfloat16* w2B    = (__hip_bfloat16*)alloc((size_t)4 * DIMC * 1024 * 2);

    // Unified weight prep: 1536 + 512 + 4096 + 4096 = 10240 tasks, 1 launch
    prep_kernel<<<10240, 256, 0, stream>>>(wq, wk, wv, bq, bk, bv, wo, w1, w2,
                                           wqkvB, bqkvF, woB, w1B, w2B);

    // CSR build (hierarchical scan)
    int nb = (N + 1023) / 1024;     // 20
    hipMemsetAsync(cnt, 0, (size_t)N * 4, stream);
    count_kernel<<<(E + 255) / 256, 256, 0, stream>>>(dstIdx, cnt, E);
    scanA_kernel<<<nb, 1024, 0, stream>>>(cnt, rowptr, bsum, N);
    scanB_kernel<<<1, 64, 0, stream>>>(bsum, nb);
    scanC_kernel<<<nb, 1024, 0, stream>>>(rowptr, bsum, N);
    hipMemsetAsync(cnt, 0, (size_t)N * 4, stream);
    scatter_kernel<<<(E + 255) / 256, 256, 0, stream>>>(srcIdx, dstIdx, rowptr, cnt, srcperm, E);

    int mt = (N + 127) / 128;        // 157
    int mt64 = (N + 63) / 64;        // 313
    int lnBlocks = (N + 3) / 4;      // 5000
    int attnBlocks = (N * 64 + 255) / 256;
    for (int l = 0; l < 4; ++l) {
        const float* xin = (l == 0) ? x : xbuf;
        ln_kernel<<<lnBlocks, 256, 0, stream>>>(xin, ln1g + l * DIMC, ln1b + l * DIMC, h, N);
        // QKV: OUT=384, BM=128 -> 471 blocks
        mfma_gemm<0, 128><<<mt * 3, 512, 0, stream>>>(
            h, wqkvB + (size_t)l * QKVC * DIMC, bqkvF + l * QKVC, nullptr,
            qkv, N, DIMC, QKVC, mt, 3);
        attn_kernel<<<attnBlocks, 256, 0, stream>>>(qkv, rowptr, srcperm, agg, N);
        // out-proj: OUT=256, K=128, BM=64 -> 626 blocks
        mfma_gemm<2, 64><<<mt64 * 2, 512, 0, stream>>>(
            agg, woB + (size_t)l * DIMC * INNERC, bo + l * DIMC, xin,
            xbuf, N, INNERC, DIMC, mt64, 2);
        ln_kernel<<<lnBlocks, 256, 0, stream>>>(xbuf, ln2g + l * DIMC, ln2b + l * DIMC, h, N);
        // FF1: OUT=1024, BM=128 -> 1256 blocks
        mfma_gemm<1, 128><<<mt * 8, 512, 0, stream>>>(
            h, w1B + (size_t)l * 1024 * DIMC, b1 + l * 1024, nullptr,
            u, N, DIMC, 1024, mt, 8);
        float* xout = (l == 3) ? (float*)d_out : xbuf;
        // FF2: OUT=256, K=1024, BM=64 -> 626 blocks, 16 K-steps
        mfma_gemm<2, 64><<<mt64 * 2, 512, 0, stream>>>(
            u, w2B + (size_t)l * DIMC * 1024, b2 + l * DIMC, xbuf,
            xout, N, 1024, DIMC, mt64, 2);
    }
}